// Round 5
// baseline (422.088 us; speedup 1.0000x reference)
//
#include <hip/hip_runtime.h>
#include <stdint.h>

typedef unsigned short u16;
typedef unsigned int   u32;
typedef unsigned long long u64;
typedef __attribute__((ext_vector_type(8))) short bf16x8;
typedef __attribute__((ext_vector_type(4))) float f32x4;

#define DEV static __device__ __forceinline__

DEV float b2f(u16 u){ u32 x = ((u32)u) << 16; float f; __builtin_memcpy(&f, &x, 4); return f; }
DEV u16 f2b(float f){ u32 x; __builtin_memcpy(&x, &f, 4); return (u16)((x + 0x7fffu + ((x >> 16) & 1u)) >> 16); }
DEV u16 f2b_trunc(float f){ u32 x; __builtin_memcpy(&x, &f, 4); return (u16)(x >> 16); }
DEV float ldf(const void* p, int i, int flg){
  return flg ? b2f(((const u16*)p)[i]) : ((const float*)p)[i];
}
// async global->LDS, 16B per lane; LDS dest = wave-uniform base + lane*16
DEV void gload_lds16(const u16* g, u16* l){
  __builtin_amdgcn_global_load_lds((const __attribute__((address_space(1))) void*)g,
                                   (__attribute__((address_space(3))) void*)l, 16, 0, 0);
}

// Dims: B=4, H=W=64, HW=4096, Cin=512, Cm=128, Ck=16, Cout=64
// Padded pixel space: 66x66 = 4356, interior pixel (h,w) -> h*66+w+67
static constexpr int HW   = 4096;
static constexpr int PPIX = 4356;

// ---------------------------------------------------------------------------
// Fused dtype-detect + BN fold. Block 512. flag: 1=bf16 inputs, 0=fp32.
// ---------------------------------------------------------------------------
__global__ void k_prep(
    const u32* __restrict__ x,
    const void* g0,const void* b0,const void* m0,const void* v0,
    const void* g1,const void* b1,const void* m1,const void* v1,
    const void* g2,const void* b2,const void* m2,const void* v2,
    const void* g3,const void* b3,const void* m3,const void* v3,
    int* __restrict__ flag, float* scale, float* shift)
{
  __shared__ int cnt;
  __shared__ int sflag;
  const int t = threadIdx.x;
  if (t == 0) cnt = 0;
  __syncthreads();
  const u32 w  = x[t];
  const u32 eb = (w >> 7) & 0xFFu;         // bf16 exponent of the LOW half
  if (eb >= 100u && eb <= 150u) atomicAdd(&cnt, 1);
  __syncthreads();
  if (t == 0){ sflag = (cnt > 384) ? 1 : 0; *flag = sflag; }
  __syncthreads();
  const int flg = sflag;
  const int set = t >> 7, c = t & 127;
  const void *gp,*bp,*mp,*vp;
  if      (set == 0){gp=g0;bp=b0;mp=m0;vp=v0;}
  else if (set == 1){gp=g1;bp=b1;mp=m1;vp=v1;}
  else if (set == 2){gp=g2;bp=b2;mp=m2;vp=v2;}
  else              {gp=g3;bp=b3;mp=m3;vp=v3;}
  const float sc = ldf(gp,c,flg) * rsqrtf(ldf(vp,c,flg) + 1e-5f);
  scale[t] = sc;
  shift[t] = ldf(bp,c,flg) - ldf(mp,c,flg) * sc;
}

// ---------------------------------------------------------------------------
// 5 small weight converts in one launch. Group = 4 elements.
// ---------------------------------------------------------------------------
__global__ void k_cvt5(
    const void* s0,const void* s1,const void* s2,const void* s3,const void* s4,
    const int* __restrict__ flagp,
    u16* d0,u16* d1,u16* d2,u16* d3,u16* d4)
{
  const int g = blockIdx.x * 256 + threadIdx.x;
  if (g >= 10752) return;
  const void* s; u16* d; int base;
  if      (g < 512) { s=s0; d=d0; base=0;    }
  else if (g < 4608){ s=s1; d=d1; base=512;  }
  else if (g < 6656){ s=s2; d=d2; base=4608; }
  else if (g < 8704){ s=s3; d=d3; base=6656; }
  else              { s=s4; d=d4; base=8704; }
  const int i = g - base;
  u64 ov;
  if (*flagp){
    ov = ((const u64*)s)[i];
  } else {
    const float4 f = ((const float4*)s)[i];
    const u16 a0 = f2b(f.x), a1 = f2b(f.y), a2 = f2b(f.z), a3 = f2b(f.w);
    ov = (u64)a0 | ((u64)a1 << 16) | ((u64)a2 << 32) | ((u64)a3 << 48);
  }
  ((u64*)d)[i] = ov;
}

// ---------------------------------------------------------------------------
// 4 3x3-weight reorders in one launch: [co][ci][rs] -> bf16 [co][rs][ci]
// ---------------------------------------------------------------------------
__global__ void k_reorder4(
    const void* w11,const void* w12,const void* w21,const void* w22,
    const int* __restrict__ flagp,
    u16* o11,u16* o12,u16* o21,u16* o22)
{
  int blk = blockIdx.x;
  const void* win; u16* wout; int cin;
  if      (blk < 2304){ win=w11; wout=o11; cin=512; }
  else if (blk < 4608){ win=w12; wout=o12; cin=512; blk-=2304; }
  else if (blk < 5184){ win=w21; wout=o21; cin=128; blk-=4608; }
  else                { win=w22; wout=o22; cin=128; blk-=5184; }
  const int idx = blk * 256 + threadIdx.x;
  const int flg = *flagp;
  const int n9 = cin * 9;
  const int co = idx / n9;
  const int rem = idx - co * n9;
  const int ci = rem / 9;
  const int rs = rem - ci * 9;
  const u16 v = flg ? ((const u16*)win)[idx] : f2b(((const float*)win)[idx]);
  wout[co * n9 + rs * cin + ci] = v;
}

// ---------------------------------------------------------------------------
// Zero halos of the 3 padded tensors in one launch.
// ---------------------------------------------------------------------------
__global__ void k_halo3(u16* __restrict__ xT, u16* __restrict__ f1, u16* __restrict__ cf)
{
  int blk = blockIdx.x;
  u16* buf; int cmask, csh;
  if      (blk < 260){ buf = xT; cmask = 511; csh = 9; }
  else if (blk < 325){ buf = f1; cmask = 127; csh = 7; blk -= 260; }
  else               { buf = cf; cmask = 127; csh = 7; blk -= 325; }
  const int tid = blk * 256 + threadIdx.x;
  const int e  = tid * 8;
  const int cc = e & cmask;
  const int rem = e >> csh;
  const int hp = rem % 260;
  const int b  = rem / 260;
  int pix;
  if      (hp < 66)  pix = hp;
  else if (hp < 132) pix = 65 * 66 + (hp - 66);
  else if (hp < 196) pix = (hp - 132 + 1) * 66;
  else               pix = (hp - 196 + 1) * 66 + 65;
  uint4 z; z.x = 0; z.y = 0; z.z = 0; z.w = 0;
  *(uint4*)(buf + ((size_t)b * PPIX + pix) * (cmask + 1) + cc) = z;
}

// ---------------------------------------------------------------------------
// x transpose: [b][512][4096] (fp32 or bf16) -> padded bf16 [b][4356][512]
// ---------------------------------------------------------------------------
__global__ __launch_bounds__(256) void k_xT(
    const void* __restrict__ src, const int* __restrict__ flagp, u16* __restrict__ dst)
{
  const int t = threadIdx.x, wave = t >> 6, lane = t & 63;
  const int pb = blockIdx.x & 31, ct = (blockIdx.x >> 5) & 7, b = blockIdx.x >> 8;
  const int c  = ct * 64 + lane;
  const int p0 = pb * 128 + wave * 32;
  const size_t sbase = ((size_t)(b * 512) + c) * 4096 + p0;

  u16 vals[32];
  if (*flagp){
    const u16* s = (const u16*)src + sbase;
    #pragma unroll
    for (int k = 0; k < 4; ++k){
      uint4 v = *(const uint4*)(s + k * 8);
      __builtin_memcpy(&vals[k * 8], &v, 16);
    }
  } else {
    const float* s = (const float*)src + sbase;
    #pragma unroll
    for (int k = 0; k < 8; ++k){
      float4 v = *(const float4*)(s + k * 4);
      vals[k*4+0] = f2b(v.x); vals[k*4+1] = f2b(v.y);
      vals[k*4+2] = f2b(v.z); vals[k*4+3] = f2b(v.w);
    }
  }
  const int hrow = (p0 >> 6) * 66 + (p0 & 63) + 67;
  u16* d = dst + ((size_t)b * PPIX + hrow) * 512 + c;
  #pragma unroll
  for (int k = 0; k < 32; ++k) d[(size_t)k * 512] = vals[k];
}

// ---------------------------------------------------------------------------
// Fused sibling 3x3 convs, LDS-tiled implicit GEMM.
// v2: 128co x 64px tiles -> grid 512 = 2 blocks/CU (inter-block overlap
// hides the per-barrier vmcnt drain; R7 had 1 block/CU -> MfmaUtil 18%).
// Wave w: co [ (w>>1)*64, +64 ), px [ (w&1)*32, +32 ): 4x2 frags.
// ---------------------------------------------------------------------------
template<int CIN_, bool PADOUT_, bool DUALB_>
__global__ __launch_bounds__(256) void k_cgemm(
    const u16* __restrict__ xA, const u16* __restrict__ xB,
    const u16* __restrict__ wA, const u16* __restrict__ wB,
    const float* __restrict__ scale, const float* __restrict__ shift,
    u16* __restrict__ outA, u16* __restrict__ outBp, u16* __restrict__ outB2)
{
  constexpr int K9   = 9 * CIN_;
  constexpr int NCH  = CIN_ / 64;
  constexpr int OPIX = PADOUT_ ? PPIX : 4096;

  __shared__ __align__(16) u16 At[128 * 64];   // 16 KB
  __shared__ __align__(16) u16 Bt[64 * 64];    // 8 KB

  const int t = threadIdx.x;
  const int w = t >> 6, lane = t & 63;
  const int l16 = lane & 15, quad = lane >> 4;

  const int cid = blockIdx.x >> 8;           // conv id
  const int rem = blockIdx.x & 255;
  const int b   = rem >> 6;
  const int p0  = (rem & 63) << 6;           // 64-px tile

  const u16* xin = cid ? xB : xA;
  const u16* wK  = cid ? wB : wA;
  const float* sc = scale + cid * 128;
  const float* sh = shift + cid * 128;

  const int rowS = t >> 3;                         // 0..31
  const int sw   = ((t & 7) ^ (rowS & 7)) << 3;    // swizzled global column

  const u16* gA[4]; u16* lA[4];
  #pragma unroll
  for (int k = 0; k < 4; ++k){
    gA[k] = wK + (size_t)(k * 32 + rowS) * K9 + sw;
    lA[k] = At + k * 2048 + w * 512;
  }
  const u16* gB[2]; u16* lB[2];
  #pragma unroll
  for (int k = 0; k < 2; ++k){
    const int px = p0 + k * 32 + rowS;
    const int h = px >> 6, wc = px & 63;
    gB[k] = xin + ((size_t)b * PPIX + h * 66 + wc) * CIN_ + sw;
    lB[k] = Bt + k * 2048 + w * 512;
  }

  f32x4 acc[4][2];
  #pragma unroll
  for (int mi = 0; mi < 4; ++mi)
    #pragma unroll
    for (int ni = 0; ni < 2; ++ni){
      acc[mi][ni][0]=0.f; acc[mi][ni][1]=0.f; acc[mi][ni][2]=0.f; acc[mi][ni][3]=0.f;
    }

  const int wc4 = (w >> 1) << 6;   // wave co base
  const int wp4 = (w & 1) << 5;    // wave px base

  #pragma unroll 1
  for (int tap = 0; tap < 9; ++tap){
    const int tb = (tap / 3) * 66 + (tap % 3);
    #pragma unroll 1
    for (int cc = 0; cc < NCH; ++cc){
      const int offA = tap * CIN_ + cc * 64;
      const int offB = tb  * CIN_ + cc * 64;
      #pragma unroll
      for (int k = 0; k < 4; ++k) gload_lds16(gA[k] + offA, lA[k]);
      #pragma unroll
      for (int k = 0; k < 2; ++k) gload_lds16(gB[k] + offB, lB[k]);
      __syncthreads();
      #pragma unroll
      for (int ks = 0; ks < 2; ++ks){
        bf16x8 af[4], bf[2];
        const int col = ((ks * 4 + quad) ^ (l16 & 7)) << 3;
        #pragma unroll
        for (int mi = 0; mi < 4; ++mi)
          af[mi] = *(const bf16x8*)(At + ((wc4 + mi * 16 + l16) << 6) + col);
        #pragma unroll
        for (int ni = 0; ni < 2; ++ni)
          bf[ni] = *(const bf16x8*)(Bt + ((wp4 + ni * 16 + l16) << 6) + col);
        #pragma unroll
        for (int mi = 0; mi < 4; ++mi)
          #pragma unroll
          for (int ni = 0; ni < 2; ++ni)
            acc[mi][ni] = __builtin_amdgcn_mfma_f32_16x16x32_bf16(af[mi], bf[ni], acc[mi][ni], 0, 0, 0);
      }
      __syncthreads();
    }
  }

  u16* outp = cid ? outBp : outA;
  #pragma unroll
  for (int mi = 0; mi < 4; ++mi){
    #pragma unroll
    for (int ni = 0; ni < 2; ++ni){
      const int px = p0 + wp4 + ni * 16 + l16;
      const int opix = PADOUT_ ? ((px >> 6) * 66 + (px & 63) + 67) : px;
      const int co4 = wc4 + mi * 16 + quad * 4;
      u16 pk[4];
      #pragma unroll
      for (int rr = 0; rr < 4; ++rr)
        pk[rr] = f2b(fmaxf(acc[mi][ni][rr] * sc[co4 + rr] + sh[co4 + rr], 0.f));
      u64 pkv; __builtin_memcpy(&pkv, pk, 8);
      *(u64*)(outp + ((size_t)b * OPIX + opix) * 128 + co4) = pkv;
      if constexpr (DUALB_){
        if (cid){
          #pragma unroll
          for (int rr = 0; rr < 4; ++rr)
            outB2[((size_t)(b * 128) + co4 + rr) * 4096 + px] = pk[rr];
        }
      }
    }
  }
}

// ---------------------------------------------------------------------------
// 1x1 conv (MFMA), one wave per 16(co) x 16(px) tile; pixel-major input.
// EPI: 2 = +bias -> channel-major bf16
//      3 = +bias -> flag ? bf16 : fp32, channel-major (d_out heads)
//      4 = +bias -> qT hi/lo bf16 pair [b][4096][16]
//      6 = CAM: gamma*acc + residual(xin2, padded pixel-major) -> padded pm out
// WPB_: weights indexed per batch (wK + b*CO*K) — used for CAM attn GEMM.
// ---------------------------------------------------------------------------
template<int CIN_, int CO_, int EPI_, bool SUM2_, bool PADIN_, bool PADOUT_, bool WPB_>
__global__ __launch_bounds__(256) void k_convT(
    const u16* __restrict__ xin, const u16* __restrict__ xin2,
    const u16* __restrict__ wK,
    const void* __restrict__ bias, const int* __restrict__ flagp,
    u16* __restrict__ outB, float* __restrict__ outF)
{
  constexpr int K    = CIN_;
  constexpr int MT   = CO_ / 16;
  constexpr int IPIX = PADIN_ ? PPIX : 4096;
  constexpr int OPIX = PADOUT_ ? PPIX : 4096;

  const int tid  = threadIdx.x;
  const int wave = tid >> 6;
  const int lane = tid & 63;
  const int l16  = lane & 15;
  const int quad = lane >> 4;

  int tile = blockIdx.x * 4 + wave;
  const int nt = tile & 255; tile >>= 8;
  const int mt = tile % MT;
  const int b  = tile / MT;

  const int p = nt * 16 + l16;
  const int h = p >> 6, wc = p & 63;

  const u16* wrow = wK + (WPB_ ? (size_t)b * CO_ * K : 0)
                       + (size_t)(mt * 16 + l16) * K + quad * 8;
  const u16* xb   = xin + (size_t)b * IPIX * CIN_ + quad * 8;

  f32x4 acc = {0.f, 0.f, 0.f, 0.f};

  const int poff = PADIN_ ? (h * 66 + wc + 67) : p;
  const u16* xrs = xb + (size_t)poff * CIN_;
  const u16* xrs2 = nullptr;
  if constexpr (SUM2_) xrs2 = xin2 + (size_t)b * IPIX * CIN_ + quad * 8 + (size_t)poff * CIN_;
  #pragma unroll
  for (int ci0 = 0; ci0 < CIN_; ci0 += 32){
    bf16x8 af = *(const bf16x8*)(wrow + ci0);
    bf16x8 bf;
    if constexpr (SUM2_){
      bf16x8 b1 = *(const bf16x8*)(xrs + ci0);
      bf16x8 b2 = *(const bf16x8*)(xrs2 + ci0);
      #pragma unroll
      for (int j = 0; j < 8; ++j)
        bf[j] = (short)f2b(b2f((u16)b1[j]) + b2f((u16)b2[j]));
    } else {
      bf = *(const bf16x8*)(xrs + ci0);
    }
    acc = __builtin_amdgcn_mfma_f32_16x16x32_bf16(af, bf, acc, 0, 0, 0);
  }

  const int flg = *flagp;

  if constexpr (EPI_ == 4){
    #pragma unroll
    for (int rr = 0; rr < 4; ++rr){
      const int co = quad * 4 + rr;   // MT == 1
      const float vv = acc[rr] + ldf(bias, co, flg);
      const u16 hb = f2b(vv);
      const float lo = vv - b2f(hb);
      const size_t qaddr = ((size_t)b * 4096 + p) * 16 + co;
      outB[qaddr] = hb;
      ((u16*)outF)[qaddr] = f2b(lo);
    }
  } else if constexpr (EPI_ == 6){
    const float g = ldf(bias, 0, flg);
    const int opix = PADOUT_ ? (h * 66 + wc + 67) : p;
    const int co4 = mt * 16 + quad * 4;
    const size_t addr = ((size_t)b * OPIX + opix) * CO_ + co4;
    u64 rv = *(const u64*)(xin2 + (size_t)b * OPIX * CO_ + (size_t)opix * CO_ + co4);
    u16 rk[4]; __builtin_memcpy(rk, &rv, 8);
    u16 pk[4];
    #pragma unroll
    for (int rr = 0; rr < 4; ++rr)
      pk[rr] = f2b(g * acc[rr] + b2f(rk[rr]));
    u64 pkv; __builtin_memcpy(&pkv, pk, 8);
    *(u64*)(outB + addr) = pkv;
  } else {
    #pragma unroll
    for (int rr = 0; rr < 4; ++rr){
      const int co = mt * 16 + quad * 4 + rr;
      const float vv = acc[rr] + ldf(bias, co, flg);
      const size_t addr = ((size_t)(b * CO_) + co) * 4096 + p;
      if constexpr (EPI_ == 2) outB[addr] = f2b(vv);
      else { if (flg) outB[addr] = f2b(vv); else outF[addr] = vv; }
    }
  }
}

// ---------------------------------------------------------------------------
// PAM flash attention v6: SINGLE-PASS online softmax with defer-max (THR=8),
// double-buffered V staging, one barrier per chunk.
// History: v3 two-pass 2-barrier 78us; v4 no-LDS 151us (L2 latency on PV
// path); v5 two-pass dbuf 1-barrier 75.8us (MfmaUtil 16.6 - barrier wasn't
// the cost; QK-load->MFMA->exp serial chain is). v6 deletes pass A entirely:
// running row max m[r], per-chunk cheap check __all(cmax<=m+8); on trigger
// (rare) full 16-lane reduce + rescale oacc/lacc by exp(m_old-m_new).
// Partial-segment contract with k_pam_comb2 unchanged (o,l,m consistent for
// any m). P bounded by e^8; l <= 1.2e7 in f32.
// Grid 1024 = b x 64 i-tile x 4 j-seg. Block 256 = 4 waves. LDS 40KB.
// ---------------------------------------------------------------------------
__global__ __launch_bounds__(256) void k_pam_flash(
    const u16* __restrict__ qTh, const u16* __restrict__ qTl,
    const u16* __restrict__ v,
    u16* __restrict__ po, float* __restrict__ pm, float* __restrict__ pl)
{
  __shared__ __align__(16) u16 vls[2][1024 * 8]; // 2 x 16 KB double buffer
  __shared__ __align__(16) u16 pls[4][128 * 8];  // 8 KB, per-wave

  const int t    = threadIdx.x;
  const int wave = t >> 6, lane = t & 63;
  const int l16  = lane & 15, quad = lane >> 4;

  const int bid = blockIdx.x;
  const int js  = bid & 3, it = (bid >> 2) & 63, b = bid >> 8;
  const int i0  = it * 64;
  const int jbase = js * 1024;

  const u16* qTbh = qTh + ((size_t)b * 4096) * 16;
  const u16* qTbl = qTl + ((size_t)b * 4096) * 16;
  const u16* vb   = v + ((size_t)b * 128) * 4096;

  bf16x8 af_hl, af_h0 = {};
  {
    const int i = i0 + wave * 16 + l16;
    const u16* src = ((quad < 2) ? qTbh : qTbl) + (size_t)i * 16 + (quad & 1) * 8;
    *(uint4*)&af_hl = *(const uint4*)src;
    if (quad < 2) af_h0 = af_hl;
  }

  // V staging addresses (per-lane global src, wave-uniform LDS dst)
  const u16* vsrcB[4];
  int vdstO[4];
  #pragma unroll
  for (int k = 0; k < 4; ++k){
    const int p = t + 256 * k;
    const int c  = ((p >> 7) << 4) | (p & 15);
    const int jl = ((p >> 6) & 1) * 32 + ((p >> 4) & 3) * 8;
    vsrcB[k] = vb + (size_t)c * 4096 + jbase + jl;
    vdstO[k] = (wave * 64 + 256 * k) * 8;
  }

  // Prologue: stage V chunk 0 into buffer 0.
  #pragma unroll
  for (int k = 0; k < 4; ++k)
    gload_lds16(vsrcB[k], &vls[0][0] + vdstO[k]);

  const short oneb = (short)0x3F80;
  const bf16x8 vones = {oneb,oneb,oneb,oneb,oneb,oneb,oneb,oneb};

  f32x4 oacc[8];
  #pragma unroll
  for (int cs = 0; cs < 8; ++cs){ oacc[cs][0]=0.f; oacc[cs][1]=0.f; oacc[cs][2]=0.f; oacc[cs][3]=0.f; }
  f32x4 lacc = {0.f, 0.f, 0.f, 0.f};
  float m[4] = {-3e38f, -3e38f, -3e38f, -3e38f};

  // Online pass: one barrier per chunk. Barrier at top drains vmcnt -> V(ch)
  // (issued last iteration) is in LDS, and all waves are done reading the
  // buffer we are about to overwrite with V(ch+1).
  #pragma unroll 1
  for (int ch = 0; ch < 16; ++ch){
    const int j0 = ch * 64;
    const int cur = ch & 1;
    __syncthreads();

    if (ch < 15){
      u16* nbuf = &vls[cur ^ 1][0];
      #pragma unroll
      for (int k = 0; k < 4; ++k)
        gload_lds16(vsrcB[k] + (j0 + 64), nbuf + vdstO[k]);
    }

    // QK for the whole chunk, keep scores in regs
    f32x4 zz[4];
    #pragma unroll
    for (int ns = 0; ns < 4; ++ns){
      const int j = jbase + j0 + ns * 16 + l16;
      bf16x8 bh, bl;
      *(uint4*)&bh = *(const uint4*)(qTbh + (size_t)j * 16 + (quad & 1) * 8);
      *(uint4*)&bl = *(const uint4*)(qTbl + (size_t)j * 16 + (quad & 1) * 8);
      f32x4 z = {0.f, 0.f, 0.f, 0.f};
      z = __builtin_amdgcn_mfma_f32_16x16x32_bf16(af_hl, bh, z, 0, 0, 0);
      z = __builtin_amdgcn_mfma_f32_16x16x32_bf16(af_h0, bl, z, 0, 0, 0);
      zz[ns] = z;
    }

    // defer-max: cheap per-lane check; rare wave-uniform rescale
    float cmax[4];
    #pragma unroll
    for (int r = 0; r < 4; ++r)
      cmax[r] = fmaxf(fmaxf(zz[0][r], zz[1][r]), fmaxf(zz[2][r], zz[3][r]));
    int ok = 1;
    #pragma unroll
    for (int r = 0; r < 4; ++r) ok &= (cmax[r] <= m[r] + 8.0f);
    if (!__all(ok)){
      #pragma unroll
      for (int r = 0; r < 4; ++r){
        float mm = cmax[r];
        mm = fmaxf(mm, __shfl_xor(mm, 1));
        mm = fmaxf(mm, __shfl_xor(mm, 2));
        mm = fmaxf(mm, __shfl_xor(mm, 4));
        mm = fmaxf(mm, __shfl_xor(mm, 8));
        mm = fmaxf(mm, m[r]);
        const float s = __expf(m[r] - mm);
        lacc[r] *= s;
        #pragma unroll
        for (int cs = 0; cs < 8; ++cs) oacc[cs][r] *= s;
        m[r] = mm;
      }
    }

    // exp + pack to per-wave pls
    #pragma unroll
    for (int ns = 0; ns < 4; ++ns){
      const int ks = ns >> 1;
      const int qp = (ns * 2 + (l16 >> 3)) & 3;
      #pragma unroll
      for (int r = 0; r < 4; ++r){
        const float p = __expf(zz[ns][r] - m[r]);
        pls[wave][(ks * 64 + qp * 16 + quad * 4 + r) * 8 + (l16 & 7)] = f2b_trunc(p);
      }
    }

    const u16* vcur = &vls[cur][0];
    #pragma unroll
    for (int ks = 0; ks < 2; ++ks){
      bf16x8 pf = *(const bf16x8*)(pls[wave] + ((ks * 64 + lane) << 3));
      #pragma unroll
      for (int cs = 0; cs < 8; ++cs){
        bf16x8 vf = *(const bf16x8*)(vcur + (((cs * 2 + ks) * 64 + lane) << 3));
        oacc[cs] = __builtin_amdgcn_mfma_f32_16x16x32_bf16(pf, vf, oacc[cs], 0, 0, 0);
      }
      lacc = __builtin_amdgcn_mfma_f32_16x16x32_bf16(pf, vones, lacc, 0, 0, 0);
    }
  }

  u16* pob = po + (size_t)bid * 64 * 128;
  #pragma unroll
  for (int cs = 0; cs < 8; ++cs)
    #pragma unroll
    for (int r = 0; r < 4; ++r)
      pob[(wave * 16 + quad * 4 + r) * 128 + cs * 16 + l16] = f2b(oacc[cs][r]);
  if (l16 == 0){
    #pragma unroll
    for (int r = 0; r < 4; ++r){
      pm[(size_t)bid * 64 + wave * 16 + quad * 4 + r] = m[r];
      pl[(size_t)bid * 64 + wave * 16 + quad * 4 + r] = lacc[r];
    }
  }
}

// ---------------------------------------------------------------------------
// PAM combine (pixel-major): merge 4 j-seg partials, gamma + residual.
// ---------------------------------------------------------------------------
__global__ __launch_bounds__(256) void k_pam_comb2(
    const u16* __restrict__ po, const float* __restrict__ pm, const float* __restrict__ pl,
    const void* __restrict__ gptr, const int* __restrict__ flagp,
    u16* __restrict__ featT)
{
  __shared__ float wgt[4][64];
  const int t  = threadIdx.x;
  const int it = blockIdx.x & 63, b = blockIdx.x >> 6;
  const int base = (b * 64 + it) * 4;
  if (t < 64){
    const float m0 = pm[(size_t)(base+0)*64 + t];
    const float m1 = pm[(size_t)(base+1)*64 + t];
    const float m2 = pm[(size_t)(base+2)*64 + t];
    const float m3 = pm[(size_t)(base+3)*64 + t];
    const float M  = fmaxf(fmaxf(m0, m1), fmaxf(m2, m3));
    const float e0 = __expf(m0 - M), e1 = __expf(m1 - M);
    const float e2 = __expf(m2 - M), e3 = __expf(m3 - M);
    const float L  = pl[(size_t)(base+0)*64+t]*e0 + pl[(size_t)(base+1)*64+t]*e1
                   + pl[(size_t)(base+2)*64+t]*e2 + pl[(size_t)(base+3)*64+t]*e3;
    const float li = 1.0f / L;
    wgt[0][t] = e0*li; wgt[1][t] = e1*li; wgt[2][t] = e2*li; wgt[3][t] = e3*li;
  }
  __syncthreads();
  const float g = ldf(gptr, 0, *flagp);
  const int c = t & 127, ih = t >> 7;
  const int i0 = it * 64;
  for (int st = 0; st < 32; ++st){
    const int il = ih + st * 2;
    float acc = 0.f;
    #pragma unroll
    for (int s = 0; s < 4; ++s)
      acc += wgt[s][il] * b2f(po[((size_t)(base+s)*64 + il)*128 + c]);
    const int i = i0 + il;
    const int pix = (i >> 6) * 66 + (i & 63) + 67;
    u16* addr = featT + ((size_t)b * PPIX + pix) * 128 + c;
    *addr = f2b(g * acc + b2f(*addr));
  }
}

// ---------------------------------------------------------------------------
// CAM energy + softmax via MFMA. Grid 32 = b(4) x ct(8); block 256.
// ---------------------------------------------------------------------------
__global__ __launch_bounds__(256) void k_cam_energy(
    const u16* __restrict__ f, u16* __restrict__ attnc)
{
  __shared__ float els[16][132];
  const int t = threadIdx.x, wave = t >> 6, lane = t & 63;
  const int l16 = lane & 15, quad = lane >> 4;
  const int ct = blockIdx.x & 7, b = blockIdx.x >> 3;
  const u16* fb = f + (size_t)b * 128 * 4096;
  const int c0 = ct * 16;
  const int d0 = wave * 32;

  f32x4 e0 = {0.f,0.f,0.f,0.f}, e1 = {0.f,0.f,0.f,0.f};
  #pragma unroll 2
  for (int k0 = 0; k0 < 4096; k0 += 32){
    bf16x8 afr, bf0, bf1;
    *(uint4*)&afr = *(const uint4*)(fb + (size_t)(c0 + l16) * 4096 + k0 + quad * 8);
    *(uint4*)&bf0 = *(const uint4*)(fb + (size_t)(d0 + l16) * 4096 + k0 + quad * 8);
    *(uint4*)&bf1 = *(const uint4*)(fb + (size_t)(d0 + 16 + l16) * 4096 + k0 + quad * 8);
    e0 = __builtin_amdgcn_mfma_f32_16x16x32_bf16(afr, bf0, e0, 0, 0, 0);
    e1 = __builtin_amdgcn_mfma_f32_16x16x32_bf16(afr, bf1, e1, 0, 0, 0);
  }
  #pragma unroll
  for (int r = 0; r < 4; ++r){
    els[quad * 4 + r][d0 + l16]      = e0[r];
    els[quad * 4 + r][d0 + 16 + l16] = e1[r];
  }
  __syncthreads();
  const int c = wave * 4 + quad, sg = l16;
  float mn = 3e38f;
  float ev[8];
  #pragma unroll
  for (int k = 0; k < 8; ++k){ ev[k] = els[c][sg * 8 + k]; mn = fminf(mn, ev[k]); }
  mn = fminf(mn, __shfl_xor(mn, 1));
  mn = fminf(mn, __shfl_xor(mn, 2));
  mn = fminf(mn, __shfl_xor(mn, 4));
  mn = fminf(mn, __shfl_xor(mn, 8));
  float s = 0.f;
  #pragma unroll
  for (int k = 0; k < 8; ++k){ ev[k] = __expf(mn - ev[k]); s += ev[k]; }
  s += __shfl_xor(s, 1); s += __shfl_xor(s, 2);
  s += __shfl_xor(s, 4); s += __shfl_xor(s, 8);
  const float inv = 1.0f / s;
  u16* dst = attnc + ((size_t)b * 128 + c0 + c) * 128 + sg * 8;
  #pragma unroll
  for (int k = 0; k < 8; ++k) dst[k] = f2b(ev[k] * inv);
}

// ---------------------------------------------------------------------------
extern "C" void kernel_launch(void* const* d_in, const int* in_sizes, int n_in,
                              void* d_out, int out_size, void* d_ws, size_t ws_size,
                              hipStream_t stream)
{
  (void)in_sizes; (void)n_in; (void)out_size; (void)ws_size;

  const void* x    = d_in[0];
  const void* w11  = d_in[1];
  const void* g11  = d_in[2];
  const void* b11  = d_in[3];
  const void* m11  = d_in[4];
  const void* v11  = d_in[5];
  const void* w12  = d_in[6];
  const void* g12  = d_in[7];
  const void* b12  = d_in[8];
  const void* m12  = d_in[9];
  const void* v12  = d_in[10];
  const void* kw   = d_in[11];
  const void* kb   = d_in[12];
  const void* vw   = d_in[13];
  const void* vb   = d_in[14];
  const void* pgam = d_in[15];
  const void* cgam = d_in[16];
  const void* w21  = d_in[17];
  const void* g21  = d_in[18];
  const void* b21  = d_in[19];
  const void* m21  = d_in[20];
  const void* v21  = d_in[21];
  const void* w22  = d_in[22];
  const void* g22  = d_in[23];
  const void* b22  = d_in[24];
  const void* m22  = d_in[25];
  const void* v22  = d_in[26];
  const void* w31  = d_in[27];
  const void* b31  = d_in[28];
  const void* w32  = d_in[29];
  const void* b32  = d_in[30];
  const void* w4   = d_in[31];
  const void* b4   = d_in[32];

  char* wsb = (char*)d_ws;
  size_t off = 0;
  auto alloc = [&](size_t bytes) -> void* {
    void* pp = wsb + off;
    off += (bytes + 255) & ~(size_t)255;
    return pp;
  };
  u16*   xT      = (u16*)alloc((size_t)4 * PPIX * 512 * 2);  // dead after trunk -> po
  u16*   feat1T  = (u16*)alloc((size_t)4 * PPIX * 128 * 2);  // padded; later pa_feat (in-place)
  u16*   feat2T  = (u16*)alloc((size_t)4 * PPIX * 128 * 2);  // padded (residual reads)
  u16*   feat2cm = (u16*)alloc((size_t)4 * 128 * HW * 2);    // channel-major (CAM energy)
  u16*   cafeatT = (u16*)alloc((size_t)4 * PPIX * 128 * 2);  // padded
  u16*   vbuf    = (u16*)alloc((size_t)4 * 128 * HW * 2);    // v cm; later pa_conv_T (unpadded)
  u16*   caconvT = (u16*)alloc((size_t)4 * HW * 128 * 2);    // unpadded pixel-major
  u16*   qTh     = (u16*)alloc((size_t)4 * HW * 16 * 2);
  u16*   qTl     = (u16*)alloc((size_t)4 * HW * 16 * 2);
  float* pm      = (float*)alloc((size_t)1024 * 64 * 4);
  float* pl      = (float*)alloc((size_t)1024 * 64 * 4);
  u16*   attnc   = (u16*)alloc((size_t)4 * 128 * 128 * 2);
  float* scale   = (float*)alloc(512 * 4);
  float* shift   = (float*)alloc(512 * 4);
  u16*   w11r    = (u16*)alloc((size_t)128 * 4608 * 2);
  u16*   w12r    = (u16*)alloc((size_t)128 * 4608 * 2);
  u16*   w21r    = (u16*)alloc((size_t)128 * 1152 * 2);
  u16*   w22r    = (u16*)alloc((size_t)128 * 1152 * 2);
  u16*   kwb     = (u16*)alloc((size_t)16 * 128 * 2);
  u16*   vwb     = (u16*)alloc((size_t)128 * 128 * 2);
  u16*   w31b    = (u16*)alloc((size_t)64 * 128 * 2);
  u16*   w32b    = (u16*)alloc((size_t)64 * 128 * 2);
  u16*   w4b     = (u16*)alloc((size_t)64 * 128 * 2);
  int*   flag    = (int*)alloc(256);
  u16*   po      = xT;   // 16.8 MB <= xT's 17.8 MB; xT dead after trunk convs

  // prep
  k_prep<<<1, 512, 0, stream>>>((const u32*)x,
                                g11,b11,m11,v11, g12,b12,m12,v12,
                                g21,b21,m21,v21, g22,b22,m22,v22, flag, scale, shift);
  k_halo3<<<390, 256, 0, stream>>>(xT, feat1T, cafeatT);
  k_xT<<<1024, 256, 0, stream>>>(x, flag, xT);
  k_reorder4<<<5760, 256, 0, stream>>>(w11, w12, w21, w22, flag, w11r, w12r, w21r, w22r);
  k_cvt5<<<42, 256, 0, stream>>>(kw, vw, w31, w32, w4, flag, kwb, vwb, w31b, w32b, w4b);

  // trunk convs, fused LDS-GEMM, 2 blocks/CU
  k_cgemm<512, true, true><<<512, 256, 0, stream>>>(
      xT, xT, w11r, w12r, scale, shift, feat1T, feat2T, feat2cm);

  // PAM
  k_convT<128,16,4,false,true,false,false><<<256,256,0,stream>>>(
      feat1T, nullptr, kwb, kb, flag, qTh, (float*)qTl);
  k_convT<128,128,2,false,true,false,false><<<2048,256,0,stream>>>(
      feat1T, nullptr, vwb, vb, flag, vbuf, nullptr);
  k_pam_flash<<<1024, 256, 0, stream>>>(qTh, qTl, vbuf, po, pm, pl);
  k_pam_comb2<<<256, 256, 0, stream>>>(po, pm, pl, pgam, flag, feat1T);  // -> pa_feat

  // CAM: MFMA energy+softmax, then MFMA GEMM attn @ f with residual epilogue
  k_cam_energy<<<32, 256, 0, stream>>>(feat2cm, attnc);
  k_convT<128,128,6,false,true,true,true><<<2048,256,0,stream>>>(
      feat2T, feat2T, attnc, cgam, flag, cafeatT, nullptr);

  // second convs, fused LDS-GEMM, 2 blocks/CU
  k_cgemm<128, false, false><<<512, 256, 0, stream>>>(
      feat1T, cafeatT, w21r, w22r, scale + 256, shift + 256, vbuf, caconvT, nullptr);

  // heads -> d_out [3][4][64][4096], channel-major, dtype per flag
  const size_t SEC = (size_t)4 * 64 * HW;
  u16*   outB = (u16*)d_out;
  float* outF = (float*)d_out;
  k_convT<128,64,3,false,false,false,false><<<1024,256,0,stream>>>(
      vbuf,    nullptr, w31b, b31, flag, outB,           outF);
  k_convT<128,64,3,false,false,false,false><<<1024,256,0,stream>>>(
      caconvT, nullptr, w32b, b32, flag, outB + SEC,     outF + SEC);
  k_convT<128,64,3,true ,false,false,false><<<1024,256,0,stream>>>(
      vbuf,    caconvT, w4b,  b4,  flag, outB + 2 * SEC, outF + 2 * SEC);
}

// Round 6
// 406.725 us; speedup vs baseline: 1.0378x; 1.0378x over previous
//
#include <hip/hip_runtime.h>
#include <stdint.h>

typedef unsigned short u16;
typedef unsigned int   u32;
typedef unsigned long long u64;
typedef __attribute__((ext_vector_type(8))) short bf16x8;
typedef __attribute__((ext_vector_type(4))) float f32x4;

#define DEV static __device__ __forceinline__

DEV float b2f(u16 u){ u32 x = ((u32)u) << 16; float f; __builtin_memcpy(&f, &x, 4); return f; }
DEV u16 f2b(float f){ u32 x; __builtin_memcpy(&x, &f, 4); return (u16)((x + 0x7fffu + ((x >> 16) & 1u)) >> 16); }
DEV u16 f2b_trunc(float f){ u32 x; __builtin_memcpy(&x, &f, 4); return (u16)(x >> 16); }
DEV float ldf(const void* p, int i, int flg){
  return flg ? b2f(((const u16*)p)[i]) : ((const float*)p)[i];
}
// async global->LDS, 16B per lane; LDS dest = wave-uniform base + lane*16
DEV void gload_lds16(const u16* g, u16* l){
  __builtin_amdgcn_global_load_lds((const __attribute__((address_space(1))) void*)g,
                                   (__attribute__((address_space(3))) void*)l, 16, 0, 0);
}

// Dims: B=4, H=W=64, HW=4096, Cin=512, Cm=128, Ck=16, Cout=64
// Padded pixel space: 66x66 = 4356, interior pixel (h,w) -> h*66+w+67
static constexpr int HW   = 4096;
static constexpr int PPIX = 4356;

// ---------------------------------------------------------------------------
// Fused dtype-detect + BN fold. Block 512. flag: 1=bf16 inputs, 0=fp32.
// ---------------------------------------------------------------------------
__global__ void k_prep(
    const u32* __restrict__ x,
    const void* g0,const void* b0,const void* m0,const void* v0,
    const void* g1,const void* b1,const void* m1,const void* v1,
    const void* g2,const void* b2,const void* m2,const void* v2,
    const void* g3,const void* b3,const void* m3,const void* v3,
    int* __restrict__ flag, float* scale, float* shift)
{
  __shared__ int cnt;
  __shared__ int sflag;
  const int t = threadIdx.x;
  if (t == 0) cnt = 0;
  __syncthreads();
  const u32 w  = x[t];
  const u32 eb = (w >> 7) & 0xFFu;         // bf16 exponent of the LOW half
  if (eb >= 100u && eb <= 150u) atomicAdd(&cnt, 1);
  __syncthreads();
  if (t == 0){ sflag = (cnt > 384) ? 1 : 0; *flag = sflag; }
  __syncthreads();
  const int flg = sflag;
  const int set = t >> 7, c = t & 127;
  const void *gp,*bp,*mp,*vp;
  if      (set == 0){gp=g0;bp=b0;mp=m0;vp=v0;}
  else if (set == 1){gp=g1;bp=b1;mp=m1;vp=v1;}
  else if (set == 2){gp=g2;bp=b2;mp=m2;vp=v2;}
  else              {gp=g3;bp=b3;mp=m3;vp=v3;}
  const float sc = ldf(gp,c,flg) * rsqrtf(ldf(vp,c,flg) + 1e-5f);
  scale[t] = sc;
  shift[t] = ldf(bp,c,flg) - ldf(mp,c,flg) * sc;
}

// ---------------------------------------------------------------------------
// 5 small weight converts in one launch. Group = 4 elements.
// ---------------------------------------------------------------------------
__global__ void k_cvt5(
    const void* s0,const void* s1,const void* s2,const void* s3,const void* s4,
    const int* __restrict__ flagp,
    u16* d0,u16* d1,u16* d2,u16* d3,u16* d4)
{
  const int g = blockIdx.x * 256 + threadIdx.x;
  if (g >= 10752) return;
  const void* s; u16* d; int base;
  if      (g < 512) { s=s0; d=d0; base=0;    }
  else if (g < 4608){ s=s1; d=d1; base=512;  }
  else if (g < 6656){ s=s2; d=d2; base=4608; }
  else if (g < 8704){ s=s3; d=d3; base=6656; }
  else              { s=s4; d=d4; base=8704; }
  const int i = g - base;
  u64 ov;
  if (*flagp){
    ov = ((const u64*)s)[i];
  } else {
    const float4 f = ((const float4*)s)[i];
    const u16 a0 = f2b(f.x), a1 = f2b(f.y), a2 = f2b(f.z), a3 = f2b(f.w);
    ov = (u64)a0 | ((u64)a1 << 16) | ((u64)a2 << 32) | ((u64)a3 << 48);
  }
  ((u64*)d)[i] = ov;
}

// ---------------------------------------------------------------------------
// 4 3x3-weight reorders in one launch: [co][ci][rs] -> bf16 [co][rs][ci]
// ---------------------------------------------------------------------------
__global__ void k_reorder4(
    const void* w11,const void* w12,const void* w21,const void* w22,
    const int* __restrict__ flagp,
    u16* o11,u16* o12,u16* o21,u16* o22)
{
  int blk = blockIdx.x;
  const void* win; u16* wout; int cin;
  if      (blk < 2304){ win=w11; wout=o11; cin=512; }
  else if (blk < 4608){ win=w12; wout=o12; cin=512; blk-=2304; }
  else if (blk < 5184){ win=w21; wout=o21; cin=128; blk-=4608; }
  else                { win=w22; wout=o22; cin=128; blk-=5184; }
  const int idx = blk * 256 + threadIdx.x;
  const int flg = *flagp;
  const int n9 = cin * 9;
  const int co = idx / n9;
  const int rem = idx - co * n9;
  const int ci = rem / 9;
  const int rs = rem - ci * 9;
  const u16 v = flg ? ((const u16*)win)[idx] : f2b(((const float*)win)[idx]);
  wout[co * n9 + rs * cin + ci] = v;
}

// ---------------------------------------------------------------------------
// Zero halos of the 3 padded tensors in one launch.
// ---------------------------------------------------------------------------
__global__ void k_halo3(u16* __restrict__ xT, u16* __restrict__ f1, u16* __restrict__ cf)
{
  int blk = blockIdx.x;
  u16* buf; int cmask, csh;
  if      (blk < 260){ buf = xT; cmask = 511; csh = 9; }
  else if (blk < 325){ buf = f1; cmask = 127; csh = 7; blk -= 260; }
  else               { buf = cf; cmask = 127; csh = 7; blk -= 325; }
  const int tid = blk * 256 + threadIdx.x;
  const int e  = tid * 8;
  const int cc = e & cmask;
  const int rem = e >> csh;
  const int hp = rem % 260;
  const int b  = rem / 260;
  int pix;
  if      (hp < 66)  pix = hp;
  else if (hp < 132) pix = 65 * 66 + (hp - 66);
  else if (hp < 196) pix = (hp - 132 + 1) * 66;
  else               pix = (hp - 196 + 1) * 66 + 65;
  uint4 z; z.x = 0; z.y = 0; z.z = 0; z.w = 0;
  *(uint4*)(buf + ((size_t)b * PPIX + pix) * (cmask + 1) + cc) = z;
}

// ---------------------------------------------------------------------------
// x transpose: [b][512][4096] (fp32 or bf16) -> padded bf16 [b][4356][512]
// ---------------------------------------------------------------------------
__global__ __launch_bounds__(256) void k_xT(
    const void* __restrict__ src, const int* __restrict__ flagp, u16* __restrict__ dst)
{
  const int t = threadIdx.x, wave = t >> 6, lane = t & 63;
  const int pb = blockIdx.x & 31, ct = (blockIdx.x >> 5) & 7, b = blockIdx.x >> 8;
  const int c  = ct * 64 + lane;
  const int p0 = pb * 128 + wave * 32;
  const size_t sbase = ((size_t)(b * 512) + c) * 4096 + p0;

  u16 vals[32];
  if (*flagp){
    const u16* s = (const u16*)src + sbase;
    #pragma unroll
    for (int k = 0; k < 4; ++k){
      uint4 v = *(const uint4*)(s + k * 8);
      __builtin_memcpy(&vals[k * 8], &v, 16);
    }
  } else {
    const float* s = (const float*)src + sbase;
    #pragma unroll
    for (int k = 0; k < 8; ++k){
      float4 v = *(const float4*)(s + k * 4);
      vals[k*4+0] = f2b(v.x); vals[k*4+1] = f2b(v.y);
      vals[k*4+2] = f2b(v.z); vals[k*4+3] = f2b(v.w);
    }
  }
  const int hrow = (p0 >> 6) * 66 + (p0 & 63) + 67;
  u16* d = dst + ((size_t)b * PPIX + hrow) * 512 + c;
  #pragma unroll
  for (int k = 0; k < 32; ++k) d[(size_t)k * 512] = vals[k];
}

// ---------------------------------------------------------------------------
// Fused sibling 3x3 convs, LDS-tiled implicit GEMM.
// v2: 128co x 64px tiles -> grid 512 = 2 blocks/CU (inter-block overlap
// hides the per-barrier vmcnt drain; R7 had 1 block/CU -> MfmaUtil 18%).
// Wave w: co [ (w>>1)*64, +64 ), px [ (w&1)*32, +32 ): 4x2 frags.
// ---------------------------------------------------------------------------
template<int CIN_, bool PADOUT_, bool DUALB_>
__global__ __launch_bounds__(256) void k_cgemm(
    const u16* __restrict__ xA, const u16* __restrict__ xB,
    const u16* __restrict__ wA, const u16* __restrict__ wB,
    const float* __restrict__ scale, const float* __restrict__ shift,
    u16* __restrict__ outA, u16* __restrict__ outBp, u16* __restrict__ outB2)
{
  constexpr int K9   = 9 * CIN_;
  constexpr int NCH  = CIN_ / 64;
  constexpr int OPIX = PADOUT_ ? PPIX : 4096;

  __shared__ __align__(16) u16 At[128 * 64];   // 16 KB
  __shared__ __align__(16) u16 Bt[64 * 64];    // 8 KB

  const int t = threadIdx.x;
  const int w = t >> 6, lane = t & 63;
  const int l16 = lane & 15, quad = lane >> 4;

  const int cid = blockIdx.x >> 8;           // conv id
  const int rem = blockIdx.x & 255;
  const int b   = rem >> 6;
  const int p0  = (rem & 63) << 6;           // 64-px tile

  const u16* xin = cid ? xB : xA;
  const u16* wK  = cid ? wB : wA;
  const float* sc = scale + cid * 128;
  const float* sh = shift + cid * 128;

  const int rowS = t >> 3;                         // 0..31
  const int sw   = ((t & 7) ^ (rowS & 7)) << 3;    // swizzled global column

  const u16* gA[4]; u16* lA[4];
  #pragma unroll
  for (int k = 0; k < 4; ++k){
    gA[k] = wK + (size_t)(k * 32 + rowS) * K9 + sw;
    lA[k] = At + k * 2048 + w * 512;
  }
  const u16* gB[2]; u16* lB[2];
  #pragma unroll
  for (int k = 0; k < 2; ++k){
    const int px = p0 + k * 32 + rowS;
    const int h = px >> 6, wc = px & 63;
    gB[k] = xin + ((size_t)b * PPIX + h * 66 + wc) * CIN_ + sw;
    lB[k] = Bt + k * 2048 + w * 512;
  }

  f32x4 acc[4][2];
  #pragma unroll
  for (int mi = 0; mi < 4; ++mi)
    #pragma unroll
    for (int ni = 0; ni < 2; ++ni){
      acc[mi][ni][0]=0.f; acc[mi][ni][1]=0.f; acc[mi][ni][2]=0.f; acc[mi][ni][3]=0.f;
    }

  const int wc4 = (w >> 1) << 6;   // wave co base
  const int wp4 = (w & 1) << 5;    // wave px base

  #pragma unroll 1
  for (int tap = 0; tap < 9; ++tap){
    const int tb = (tap / 3) * 66 + (tap % 3);
    #pragma unroll 1
    for (int cc = 0; cc < NCH; ++cc){
      const int offA = tap * CIN_ + cc * 64;
      const int offB = tb  * CIN_ + cc * 64;
      #pragma unroll
      for (int k = 0; k < 4; ++k) gload_lds16(gA[k] + offA, lA[k]);
      #pragma unroll
      for (int k = 0; k < 2; ++k) gload_lds16(gB[k] + offB, lB[k]);
      __syncthreads();
      #pragma unroll
      for (int ks = 0; ks < 2; ++ks){
        bf16x8 af[4], bf[2];
        const int col = ((ks * 4 + quad) ^ (l16 & 7)) << 3;
        #pragma unroll
        for (int mi = 0; mi < 4; ++mi)
          af[mi] = *(const bf16x8*)(At + ((wc4 + mi * 16 + l16) << 6) + col);
        #pragma unroll
        for (int ni = 0; ni < 2; ++ni)
          bf[ni] = *(const bf16x8*)(Bt + ((wp4 + ni * 16 + l16) << 6) + col);
        #pragma unroll
        for (int mi = 0; mi < 4; ++mi)
          #pragma unroll
          for (int ni = 0; ni < 2; ++ni)
            acc[mi][ni] = __builtin_amdgcn_mfma_f32_16x16x32_bf16(af[mi], bf[ni], acc[mi][ni], 0, 0, 0);
      }
      __syncthreads();
    }
  }

  u16* outp = cid ? outBp : outA;
  #pragma unroll
  for (int mi = 0; mi < 4; ++mi){
    #pragma unroll
    for (int ni = 0; ni < 2; ++ni){
      const int px = p0 + wp4 + ni * 16 + l16;
      const int opix = PADOUT_ ? ((px >> 6) * 66 + (px & 63) + 67) : px;
      const int co4 = wc4 + mi * 16 + quad * 4;
      u16 pk[4];
      #pragma unroll
      for (int rr = 0; rr < 4; ++rr)
        pk[rr] = f2b(fmaxf(acc[mi][ni][rr] * sc[co4 + rr] + sh[co4 + rr], 0.f));
      u64 pkv; __builtin_memcpy(&pkv, pk, 8);
      *(u64*)(outp + ((size_t)b * OPIX + opix) * 128 + co4) = pkv;
      if constexpr (DUALB_){
        if (cid){
          #pragma unroll
          for (int rr = 0; rr < 4; ++rr)
            outB2[((size_t)(b * 128) + co4 + rr) * 4096 + px] = pk[rr];
        }
      }
    }
  }
}

// ---------------------------------------------------------------------------
// 1x1 conv (MFMA), one wave per 16(co) x 16(px) tile; pixel-major input.
// EPI: 2 = +bias -> channel-major bf16
//      3 = +bias -> flag ? bf16 : fp32, channel-major (d_out heads)
//      4 = +bias -> qT hi/lo bf16 pair [b][4096][16]
//      6 = CAM: gamma*acc + residual(xin2, padded pixel-major) -> padded pm out
// WPB_: weights indexed per batch (wK + b*CO*K) — used for CAM attn GEMM.
// ---------------------------------------------------------------------------
template<int CIN_, int CO_, int EPI_, bool SUM2_, bool PADIN_, bool PADOUT_, bool WPB_>
__global__ __launch_bounds__(256) void k_convT(
    const u16* __restrict__ xin, const u16* __restrict__ xin2,
    const u16* __restrict__ wK,
    const void* __restrict__ bias, const int* __restrict__ flagp,
    u16* __restrict__ outB, float* __restrict__ outF)
{
  constexpr int K    = CIN_;
  constexpr int MT   = CO_ / 16;
  constexpr int IPIX = PADIN_ ? PPIX : 4096;
  constexpr int OPIX = PADOUT_ ? PPIX : 4096;

  const int tid  = threadIdx.x;
  const int wave = tid >> 6;
  const int lane = tid & 63;
  const int l16  = lane & 15;
  const int quad = lane >> 4;

  int tile = blockIdx.x * 4 + wave;
  const int nt = tile & 255; tile >>= 8;
  const int mt = tile % MT;
  const int b  = tile / MT;

  const int p = nt * 16 + l16;
  const int h = p >> 6, wc = p & 63;

  const u16* wrow = wK + (WPB_ ? (size_t)b * CO_ * K : 0)
                       + (size_t)(mt * 16 + l16) * K + quad * 8;
  const u16* xb   = xin + (size_t)b * IPIX * CIN_ + quad * 8;

  f32x4 acc = {0.f, 0.f, 0.f, 0.f};

  const int poff = PADIN_ ? (h * 66 + wc + 67) : p;
  const u16* xrs = xb + (size_t)poff * CIN_;
  const u16* xrs2 = nullptr;
  if constexpr (SUM2_) xrs2 = xin2 + (size_t)b * IPIX * CIN_ + quad * 8 + (size_t)poff * CIN_;
  #pragma unroll
  for (int ci0 = 0; ci0 < CIN_; ci0 += 32){
    bf16x8 af = *(const bf16x8*)(wrow + ci0);
    bf16x8 bf;
    if constexpr (SUM2_){
      bf16x8 b1 = *(const bf16x8*)(xrs + ci0);
      bf16x8 b2 = *(const bf16x8*)(xrs2 + ci0);
      #pragma unroll
      for (int j = 0; j < 8; ++j)
        bf[j] = (short)f2b(b2f((u16)b1[j]) + b2f((u16)b2[j]));
    } else {
      bf = *(const bf16x8*)(xrs + ci0);
    }
    acc = __builtin_amdgcn_mfma_f32_16x16x32_bf16(af, bf, acc, 0, 0, 0);
  }

  const int flg = *flagp;

  if constexpr (EPI_ == 4){
    #pragma unroll
    for (int rr = 0; rr < 4; ++rr){
      const int co = quad * 4 + rr;   // MT == 1
      const float vv = acc[rr] + ldf(bias, co, flg);
      const u16 hb = f2b(vv);
      const float lo = vv - b2f(hb);
      const size_t qaddr = ((size_t)b * 4096 + p) * 16 + co;
      outB[qaddr] = hb;
      ((u16*)outF)[qaddr] = f2b(lo);
    }
  } else if constexpr (EPI_ == 6){
    const float g = ldf(bias, 0, flg);
    const int opix = PADOUT_ ? (h * 66 + wc + 67) : p;
    const int co4 = mt * 16 + quad * 4;
    const size_t addr = ((size_t)b * OPIX + opix) * CO_ + co4;
    u64 rv = *(const u64*)(xin2 + (size_t)b * OPIX * CO_ + (size_t)opix * CO_ + co4);
    u16 rk[4]; __builtin_memcpy(rk, &rv, 8);
    u16 pk[4];
    #pragma unroll
    for (int rr = 0; rr < 4; ++rr)
      pk[rr] = f2b(g * acc[rr] + b2f(rk[rr]));
    u64 pkv; __builtin_memcpy(&pkv, pk, 8);
    *(u64*)(outB + addr) = pkv;
  } else {
    #pragma unroll
    for (int rr = 0; rr < 4; ++rr){
      const int co = mt * 16 + quad * 4 + rr;
      const float vv = acc[rr] + ldf(bias, co, flg);
      const size_t addr = ((size_t)(b * CO_) + co) * 4096 + p;
      if constexpr (EPI_ == 2) outB[addr] = f2b(vv);
      else { if (flg) outB[addr] = f2b(vv); else outF[addr] = vv; }
    }
  }
}

// ---------------------------------------------------------------------------
// PAM flash attention v7: TWO-PASS (v5 structure) + K-fragment LDS staging.
// History: v3 78us; v4 no-LDS 151us; v5 dbuf-V 1-barrier 75.8us; v6
// defer-max single-pass 91.7us (VGPR 52->72, occupancy 40->24% - REVERTED).
// v7 = v5 + kls: pass B's on-demand global qTh/qTl fragment loads (8 L2-
// latency loads/chunk/wave, identical across waves) become prefetched LDS
// reads riding the existing chunk-ahead double-buffer + barrier. K/chunk =
// 4KB (64 rows x 16ch x hi+lo). Pass A keeps global loads (barrier-free,
// compiler-pipelined). LDS 48KB -> 3 blocks/CU cap (measured residency was
// ~3.2 anyway).
// Grid 1024 = b x 64 i-tile x 4 j-seg. Block 256 = 4 waves.
// ---------------------------------------------------------------------------
__global__ __launch_bounds__(256) void k_pam_flash(
    const u16* __restrict__ qTh, const u16* __restrict__ qTl,
    const u16* __restrict__ v,
    u16* __restrict__ po, float* __restrict__ pm, float* __restrict__ pl)
{
  __shared__ __align__(16) u16 vls[2][1024 * 8]; // 2 x 16 KB V double buffer
  __shared__ __align__(16) u16 kls[2][128 * 16]; // 2 x 4 KB K double buffer (hi rows 0-63, lo rows 64-127)
  __shared__ __align__(16) u16 pls[4][128 * 8];  // 8 KB, per-wave

  const int t    = threadIdx.x;
  const int wave = t >> 6, lane = t & 63;
  const int l16  = lane & 15, quad = lane >> 4;

  const int bid = blockIdx.x;
  const int js  = bid & 3, it = (bid >> 2) & 63, b = bid >> 8;
  const int i0  = it * 64;
  const int jbase = js * 1024;

  const u16* qTbh = qTh + ((size_t)b * 4096) * 16;
  const u16* qTbl = qTl + ((size_t)b * 4096) * 16;
  const u16* vb   = v + ((size_t)b * 128) * 4096;

  bf16x8 af_hl, af_h0 = {};
  {
    const int i = i0 + wave * 16 + l16;
    const u16* src = ((quad < 2) ? qTbh : qTbl) + (size_t)i * 16 + (quad & 1) * 8;
    *(uint4*)&af_hl = *(const uint4*)src;
    if (quad < 2) af_h0 = af_hl;
  }

  // V staging addresses (per-lane global src, wave-uniform LDS dst)
  const u16* vsrcB[4];
  int vdstO[4];
  #pragma unroll
  for (int k = 0; k < 4; ++k){
    const int p = t + 256 * k;
    const int c  = ((p >> 7) << 4) | (p & 15);
    const int jl = ((p >> 6) & 1) * 32 + ((p >> 4) & 3) * 8;
    vsrcB[k] = vb + (size_t)c * 4096 + jbase + jl;
    vdstO[k] = (wave * 64 + 256 * k) * 8;
  }
  // K staging: thread t covers 16B; t<128 -> hi rows, t>=128 -> lo rows.
  // Chunk cc source offset = cc*1024 u16 (64 rows x 16).
  const u16* ksrc = ((t & 128) ? qTbl : qTbh) + (size_t)jbase * 16 + (t & 127) * 8;
  const int  kdstO = t * 8;

  // Prologue: stage V(0) + K(0) into buffer 0; lands during pass A.
  #pragma unroll
  for (int k = 0; k < 4; ++k)
    gload_lds16(vsrcB[k], &vls[0][0] + vdstO[k]);
  gload_lds16(ksrc, &kls[0][0] + kdstO);

  // Pass A: segment row max (hi-only QK), global loads, barrier-free.
  float mloc[4] = {-3e38f, -3e38f, -3e38f, -3e38f};
  #pragma unroll 1
  for (int ch = 0; ch < 16; ++ch){
    #pragma unroll
    for (int ns = 0; ns < 4; ++ns){
      const int j = jbase + ch * 64 + ns * 16 + l16;
      bf16x8 bh;
      *(uint4*)&bh = *(const uint4*)(qTbh + (size_t)j * 16 + (quad & 1) * 8);
      f32x4 z = {0.f, 0.f, 0.f, 0.f};
      z = __builtin_amdgcn_mfma_f32_16x16x32_bf16(af_hl, bh, z, 0, 0, 0);
      #pragma unroll
      for (int r = 0; r < 4; ++r) mloc[r] = fmaxf(mloc[r], z[r]);
    }
  }
  float mrow[4];
  #pragma unroll
  for (int r = 0; r < 4; ++r){
    float mm = mloc[r];
    mm = fmaxf(mm, __shfl_xor(mm, 1));
    mm = fmaxf(mm, __shfl_xor(mm, 2));
    mm = fmaxf(mm, __shfl_xor(mm, 4));
    mm = fmaxf(mm, __shfl_xor(mm, 8));
    mrow[r] = mm;
  }

  const short oneb = (short)0x3F80;
  const bf16x8 vones = {oneb,oneb,oneb,oneb,oneb,oneb,oneb,oneb};

  f32x4 oacc[8];
  #pragma unroll
  for (int cs = 0; cs < 8; ++cs){ oacc[cs][0]=0.f; oacc[cs][1]=0.f; oacc[cs][2]=0.f; oacc[cs][3]=0.f; }
  f32x4 lacc = {0.f, 0.f, 0.f, 0.f};

  // Pass B: one barrier per chunk. Barrier at top drains vmcnt -> V(ch),K(ch)
  // (issued last iteration) are in LDS, and all waves are done reading the
  // buffers about to be overwritten with chunk ch+1.
  #pragma unroll 1
  for (int ch = 0; ch < 16; ++ch){
    const int j0 = ch * 64;
    const int cur = ch & 1;
    __syncthreads();

    if (ch < 15){
      u16* nvbuf = &vls[cur ^ 1][0];
      #pragma unroll
      for (int k = 0; k < 4; ++k)
        gload_lds16(vsrcB[k] + (j0 + 64), nvbuf + vdstO[k]);
      gload_lds16(ksrc + (ch + 1) * 1024, &kls[cur ^ 1][0] + kdstO);
    }

    const u16* kcur = &kls[cur][0];
    #pragma unroll
    for (int ns = 0; ns < 4; ++ns){
      const int rowoff = (ns * 16 + l16) * 16 + (quad & 1) * 8;
      bf16x8 bh, bl;
      *(uint4*)&bh = *(const uint4*)(kcur + rowoff);
      *(uint4*)&bl = *(const uint4*)(kcur + 1024 + rowoff);
      f32x4 z = {0.f, 0.f, 0.f, 0.f};
      z = __builtin_amdgcn_mfma_f32_16x16x32_bf16(af_hl, bh, z, 0, 0, 0);
      z = __builtin_amdgcn_mfma_f32_16x16x32_bf16(af_h0, bl, z, 0, 0, 0);
      const int ks = ns >> 1;
      const int qp = (ns * 2 + (l16 >> 3)) & 3;
      #pragma unroll
      for (int r = 0; r < 4; ++r){
        const float p = __expf(z[r] - mrow[r]);
        pls[wave][(ks * 64 + qp * 16 + quad * 4 + r) * 8 + (l16 & 7)] = f2b_trunc(p);
      }
    }

    const u16* vcur = &vls[cur][0];
    #pragma unroll
    for (int ks = 0; ks < 2; ++ks){
      bf16x8 pf = *(const bf16x8*)(pls[wave] + ((ks * 64 + lane) << 3));
      #pragma unroll
      for (int cs = 0; cs < 8; ++cs){
        bf16x8 vf = *(const bf16x8*)(vcur + (((cs * 2 + ks) * 64 + lane) << 3));
        oacc[cs] = __builtin_amdgcn_mfma_f32_16x16x32_bf16(pf, vf, oacc[cs], 0, 0, 0);
      }
      lacc = __builtin_amdgcn_mfma_f32_16x16x32_bf16(pf, vones, lacc, 0, 0, 0);
    }
  }

  u16* pob = po + (size_t)bid * 64 * 128;
  #pragma unroll
  for (int cs = 0; cs < 8; ++cs)
    #pragma unroll
    for (int r = 0; r < 4; ++r)
      pob[(wave * 16 + quad * 4 + r) * 128 + cs * 16 + l16] = f2b(oacc[cs][r]);
  if (l16 == 0){
    #pragma unroll
    for (int r = 0; r < 4; ++r){
      pm[(size_t)bid * 64 + wave * 16 + quad * 4 + r] = mrow[r];
      pl[(size_t)bid * 64 + wave * 16 + quad * 4 + r] = lacc[r];
    }
  }
}

// ---------------------------------------------------------------------------
// PAM combine (pixel-major): merge 4 j-seg partials, gamma + residual.
// ---------------------------------------------------------------------------
__global__ __launch_bounds__(256) void k_pam_comb2(
    const u16* __restrict__ po, const float* __restrict__ pm, const float* __restrict__ pl,
    const void* __restrict__ gptr, const int* __restrict__ flagp,
    u16* __restrict__ featT)
{
  __shared__ float wgt[4][64];
  const int t  = threadIdx.x;
  const int it = blockIdx.x & 63, b = blockIdx.x >> 6;
  const int base = (b * 64 + it) * 4;
  if (t < 64){
    const float m0 = pm[(size_t)(base+0)*64 + t];
    const float m1 = pm[(size_t)(base+1)*64 + t];
    const float m2 = pm[(size_t)(base+2)*64 + t];
    const float m3 = pm[(size_t)(base+3)*64 + t];
    const float M  = fmaxf(fmaxf(m0, m1), fmaxf(m2, m3));
    const float e0 = __expf(m0 - M), e1 = __expf(m1 - M);
    const float e2 = __expf(m2 - M), e3 = __expf(m3 - M);
    const float L  = pl[(size_t)(base+0)*64+t]*e0 + pl[(size_t)(base+1)*64+t]*e1
                   + pl[(size_t)(base+2)*64+t]*e2 + pl[(size_t)(base+3)*64+t]*e3;
    const float li = 1.0f / L;
    wgt[0][t] = e0*li; wgt[1][t] = e1*li; wgt[2][t] = e2*li; wgt[3][t] = e3*li;
  }
  __syncthreads();
  const float g = ldf(gptr, 0, *flagp);
  const int c = t & 127, ih = t >> 7;
  const int i0 = it * 64;
  for (int st = 0; st < 32; ++st){
    const int il = ih + st * 2;
    float acc = 0.f;
    #pragma unroll
    for (int s = 0; s < 4; ++s)
      acc += wgt[s][il] * b2f(po[((size_t)(base+s)*64 + il)*128 + c]);
    const int i = i0 + il;
    const int pix = (i >> 6) * 66 + (i & 63) + 67;
    u16* addr = featT + ((size_t)b * PPIX + pix) * 128 + c;
    *addr = f2b(g * acc + b2f(*addr));
  }
}

// ---------------------------------------------------------------------------
// CAM energy + softmax via MFMA. Grid 32 = b(4) x ct(8); block 256.
// ---------------------------------------------------------------------------
__global__ __launch_bounds__(256) void k_cam_energy(
    const u16* __restrict__ f, u16* __restrict__ attnc)
{
  __shared__ float els[16][132];
  const int t = threadIdx.x, wave = t >> 6, lane = t & 63;
  const int l16 = lane & 15, quad = lane >> 4;
  const int ct = blockIdx.x & 7, b = blockIdx.x >> 3;
  const u16* fb = f + (size_t)b * 128 * 4096;
  const int c0 = ct * 16;
  const int d0 = wave * 32;

  f32x4 e0 = {0.f,0.f,0.f,0.f}, e1 = {0.f,0.f,0.f,0.f};
  #pragma unroll 2
  for (int k0 = 0; k0 < 4096; k0 += 32){
    bf16x8 afr, bf0, bf1;
    *(uint4*)&afr = *(const uint4*)(fb + (size_t)(c0 + l16) * 4096 + k0 + quad * 8);
    *(uint4*)&bf0 = *(const uint4*)(fb + (size_t)(d0 + l16) * 4096 + k0 + quad * 8);
    *(uint4*)&bf1 = *(const uint4*)(fb + (size_t)(d0 + 16 + l16) * 4096 + k0 + quad * 8);
    e0 = __builtin_amdgcn_mfma_f32_16x16x32_bf16(afr, bf0, e0, 0, 0, 0);
    e1 = __builtin_amdgcn_mfma_f32_16x16x32_bf16(afr, bf1, e1, 0, 0, 0);
  }
  #pragma unroll
  for (int r = 0; r < 4; ++r){
    els[quad * 4 + r][d0 + l16]      = e0[r];
    els[quad * 4 + r][d0 + 16 + l16] = e1[r];
  }
  __syncthreads();
  const int c = wave * 4 + quad, sg = l16;
  float mn = 3e38f;
  float ev[8];
  #pragma unroll
  for (int k = 0; k < 8; ++k){ ev[k] = els[c][sg * 8 + k]; mn = fminf(mn, ev[k]); }
  mn = fminf(mn, __shfl_xor(mn, 1));
  mn = fminf(mn, __shfl_xor(mn, 2));
  mn = fminf(mn, __shfl_xor(mn, 4));
  mn = fminf(mn, __shfl_xor(mn, 8));
  float s = 0.f;
  #pragma unroll
  for (int k = 0; k < 8; ++k){ ev[k] = __expf(mn - ev[k]); s += ev[k]; }
  s += __shfl_xor(s, 1); s += __shfl_xor(s, 2);
  s += __shfl_xor(s, 4); s += __shfl_xor(s, 8);
  const float inv = 1.0f / s;
  u16* dst = attnc + ((size_t)b * 128 + c0 + c) * 128 + sg * 8;
  #pragma unroll
  for (int k = 0; k < 8; ++k) dst[k] = f2b(ev[k] * inv);
}

// ---------------------------------------------------------------------------
extern "C" void kernel_launch(void* const* d_in, const int* in_sizes, int n_in,
                              void* d_out, int out_size, void* d_ws, size_t ws_size,
                              hipStream_t stream)
{
  (void)in_sizes; (void)n_in; (void)out_size; (void)ws_size;

  const void* x    = d_in[0];
  const void* w11  = d_in[1];
  const void* g11  = d_in[2];
  const void* b11  = d_in[3];
  const void* m11  = d_in[4];
  const void* v11  = d_in[5];
  const void* w12  = d_in[6];
  const void* g12  = d_in[7];
  const void* b12  = d_in[8];
  const void* m12  = d_in[9];
  const void* v12  = d_in[10];
  const void* kw   = d_in[11];
  const void* kb   = d_in[12];
  const void* vw   = d_in[13];
  const void* vb   = d_in[14];
  const void* pgam = d_in[15];
  const void* cgam = d_in[16];
  const void* w21  = d_in[17];
  const void* g21  = d_in[18];
  const void* b21  = d_in[19];
  const void* m21  = d_in[20];
  const void* v21  = d_in[21];
  const void* w22  = d_in[22];
  const void* g22  = d_in[23];
  const void* b22  = d_in[24];
  const void* m22  = d_in[25];
  const void* v22  = d_in[26];
  const void* w31  = d_in[27];
  const void* b31  = d_in[28];
  const void* w32  = d_in[29];
  const void* b32  = d_in[30];
  const void* w4   = d_in[31];
  const void* b4   = d_in[32];

  char* wsb = (char*)d_ws;
  size_t off = 0;
  auto alloc = [&](size_t bytes) -> void* {
    void* pp = wsb + off;
    off += (bytes + 255) & ~(size_t)255;
    return pp;
  };
  u16*   xT      = (u16*)alloc((size_t)4 * PPIX * 512 * 2);  // dead after trunk -> po
  u16*   feat1T  = (u16*)alloc((size_t)4 * PPIX * 128 * 2);  // padded; later pa_feat (in-place)
  u16*   feat2T  = (u16*)alloc((size_t)4 * PPIX * 128 * 2);  // padded (residual reads)
  u16*   feat2cm = (u16*)alloc((size_t)4 * 128 * HW * 2);    // channel-major (CAM energy)
  u16*   cafeatT = (u16*)alloc((size_t)4 * PPIX * 128 * 2);  // padded
  u16*   vbuf    = (u16*)alloc((size_t)4 * 128 * HW * 2);    // v cm; later pa_conv_T (unpadded)
  u16*   caconvT = (u16*)alloc((size_t)4 * HW * 128 * 2);    // unpadded pixel-major
  u16*   qTh     = (u16*)alloc((size_t)4 * HW * 16 * 2);
  u16*   qTl     = (u16*)alloc((size_t)4 * HW * 16 * 2);
  float* pm      = (float*)alloc((size_t)1024 * 64 * 4);
  float* pl      = (float*)alloc((size_t)1024 * 64 * 4);
  u16*   attnc   = (u16*)alloc((size_t)4 * 128 * 128 * 2);
  float* scale   = (float*)alloc(512 * 4);
  float* shift   = (float*)alloc(512 * 4);
  u16*   w11r    = (u16*)alloc((size_t)128 * 4608 * 2);
  u16*   w12r    = (u16*)alloc((size_t)128 * 4608 * 2);
  u16*   w21r    = (u16*)alloc((size_t)128 * 1152 * 2);
  u16*   w22r    = (u16*)alloc((size_t)128 * 1152 * 2);
  u16*   kwb     = (u16*)alloc((size_t)16 * 128 * 2);
  u16*   vwb     = (u16*)alloc((size_t)128 * 128 * 2);
  u16*   w31b    = (u16*)alloc((size_t)64 * 128 * 2);
  u16*   w32b    = (u16*)alloc((size_t)64 * 128 * 2);
  u16*   w4b     = (u16*)alloc((size_t)64 * 128 * 2);
  int*   flag    = (int*)alloc(256);
  u16*   po      = xT;   // 16.8 MB <= xT's 17.8 MB; xT dead after trunk convs

  // prep
  k_prep<<<1, 512, 0, stream>>>((const u32*)x,
                                g11,b11,m11,v11, g12,b12,m12,v12,
                                g21,b21,m21,v21, g22,b22,m22,v22, flag, scale, shift);
  k_halo3<<<390, 256, 0, stream>>>(xT, feat1T, cafeatT);
  k_xT<<<1024, 256, 0, stream>>>(x, flag, xT);
  k_reorder4<<<5760, 256, 0, stream>>>(w11, w12, w21, w22, flag, w11r, w12r, w21r, w22r);
  k_cvt5<<<42, 256, 0, stream>>>(kw, vw, w31, w32, w4, flag, kwb, vwb, w31b, w32b, w4b);

  // trunk convs, fused LDS-GEMM, 2 blocks/CU
  k_cgemm<512, true, true><<<512, 256, 0, stream>>>(
      xT, xT, w11r, w12r, scale, shift, feat1T, feat2T, feat2cm);

  // PAM
  k_convT<128,16,4,false,true,false,false><<<256,256,0,stream>>>(
      feat1T, nullptr, kwb, kb, flag, qTh, (float*)qTl);
  k_convT<128,128,2,false,true,false,false><<<2048,256,0,stream>>>(
      feat1T, nullptr, vwb, vb, flag, vbuf, nullptr);
  k_pam_flash<<<1024, 256, 0, stream>>>(qTh, qTl, vbuf, po, pm, pl);
  k_pam_comb2<<<256, 256, 0, stream>>>(po, pm, pl, pgam, flag, feat1T);  // -> pa_feat

  // CAM: MFMA energy+softmax, then MFMA GEMM attn @ f with residual epilogue
  k_cam_energy<<<32, 256, 0, stream>>>(feat2cm, attnc);
  k_convT<128,128,6,false,true,true,true><<<2048,256,0,stream>>>(
      feat2T, feat2T, attnc, cgam, flag, cafeatT, nullptr);

  // second convs, fused LDS-GEMM, 2 blocks/CU
  k_cgemm<128, false, false><<<512, 256, 0, stream>>>(
      feat1T, cafeatT, w21r, w22r, scale + 256, shift + 256, vbuf, caconvT, nullptr);

  // heads -> d_out [3][4][64][4096], channel-major, dtype per flag
  const size_t SEC = (size_t)4 * 64 * HW;
  u16*   outB = (u16*)d_out;
  float* outF = (float*)d_out;
  k_convT<128,64,3,false,false,false,false><<<1024,256,0,stream>>>(
      vbuf,    nullptr, w31b, b31, flag, outB,           outF);
  k_convT<128,64,3,false,false,false,false><<<1024,256,0,stream>>>(
      caconvT, nullptr, w32b, b32, flag, outB + SEC,     outF + SEC);
  k_convT<128,64,3,true ,false,false,false><<<1024,256,0,stream>>>(
      vbuf,    caconvT, w4b,  b4,  flag, outB + 2 * SEC, outF + 2 * SEC);
}

// Round 8
// 384.786 us; speedup vs baseline: 1.0969x; 1.0570x over previous
//
#include <hip/hip_runtime.h>
#include <stdint.h>

typedef unsigned short u16;
typedef unsigned int   u32;
typedef unsigned long long u64;
typedef __attribute__((ext_vector_type(8))) short bf16x8;
typedef __attribute__((ext_vector_type(4))) float f32x4;

#define DEV static __device__ __forceinline__

DEV float b2f(u16 u){ u32 x = ((u32)u) << 16; float f; __builtin_memcpy(&f, &x, 4); return f; }
DEV u16 f2b(float f){ u32 x; __builtin_memcpy(&x, &f, 4); return (u16)((x + 0x7fffu + ((x >> 16) & 1u)) >> 16); }
DEV u16 f2b_trunc(float f){ u32 x; __builtin_memcpy(&x, &f, 4); return (u16)(x >> 16); }
DEV float ldf(const void* p, int i, int flg){
  return flg ? b2f(((const u16*)p)[i]) : ((const float*)p)[i];
}
// async global->LDS, 16B per lane; LDS dest = wave-uniform base + lane*16
DEV void gload_lds16(const u16* g, u16* l){
  __builtin_amdgcn_global_load_lds((const __attribute__((address_space(1))) void*)g,
                                   (__attribute__((address_space(3))) void*)l, 16, 0, 0);
}

// Dims: B=4, H=W=64, HW=4096, Cin=512, Cm=128, Ck=16, Cout=64
// Padded pixel space: 66x66 = 4356, interior pixel (h,w) -> h*66+w+67
static constexpr int HW   = 4096;
static constexpr int PPIX = 4356;

// ---------------------------------------------------------------------------
// Fused dtype-detect + BN fold. Block 512. flag: 1=bf16 inputs, 0=fp32.
// ---------------------------------------------------------------------------
__global__ void k_prep(
    const u32* __restrict__ x,
    const void* g0,const void* b0,const void* m0,const void* v0,
    const void* g1,const void* b1,const void* m1,const void* v1,
    const void* g2,const void* b2,const void* m2,const void* v2,
    const void* g3,const void* b3,const void* m3,const void* v3,
    int* __restrict__ flag, float* scale, float* shift)
{
  __shared__ int cnt;
  __shared__ int sflag;
  const int t = threadIdx.x;
  if (t == 0) cnt = 0;
  __syncthreads();
  const u32 w  = x[t];
  const u32 eb = (w >> 7) & 0xFFu;         // bf16 exponent of the LOW half
  if (eb >= 100u && eb <= 150u) atomicAdd(&cnt, 1);
  __syncthreads();
  if (t == 0){ sflag = (cnt > 384) ? 1 : 0; *flag = sflag; }
  __syncthreads();
  const int flg = sflag;
  const int set = t >> 7, c = t & 127;
  const void *gp,*bp,*mp,*vp;
  if      (set == 0){gp=g0;bp=b0;mp=m0;vp=v0;}
  else if (set == 1){gp=g1;bp=b1;mp=m1;vp=v1;}
  else if (set == 2){gp=g2;bp=b2;mp=m2;vp=v2;}
  else              {gp=g3;bp=b3;mp=m3;vp=v3;}
  const float sc = ldf(gp,c,flg) * rsqrtf(ldf(vp,c,flg) + 1e-5f);
  scale[t] = sc;
  shift[t] = ldf(bp,c,flg) - ldf(mp,c,flg) * sc;
}

// ---------------------------------------------------------------------------
// 5 small weight converts in one launch. Group = 4 elements.
// ---------------------------------------------------------------------------
__global__ void k_cvt5(
    const void* s0,const void* s1,const void* s2,const void* s3,const void* s4,
    const int* __restrict__ flagp,
    u16* d0,u16* d1,u16* d2,u16* d3,u16* d4)
{
  const int g = blockIdx.x * 256 + threadIdx.x;
  if (g >= 10752) return;
  const void* s; u16* d; int base;
  if      (g < 512) { s=s0; d=d0; base=0;    }
  else if (g < 4608){ s=s1; d=d1; base=512;  }
  else if (g < 6656){ s=s2; d=d2; base=4608; }
  else if (g < 8704){ s=s3; d=d3; base=6656; }
  else              { s=s4; d=d4; base=8704; }
  const int i = g - base;
  u64 ov;
  if (*flagp){
    ov = ((const u64*)s)[i];
  } else {
    const float4 f = ((const float4*)s)[i];
    const u16 a0 = f2b(f.x), a1 = f2b(f.y), a2 = f2b(f.z), a3 = f2b(f.w);
    ov = (u64)a0 | ((u64)a1 << 16) | ((u64)a2 << 32) | ((u64)a3 << 48);
  }
  ((u64*)d)[i] = ov;
}

// ---------------------------------------------------------------------------
// 4 3x3-weight reorders in one launch: [co][ci][rs] -> bf16 [co][rs][ci]
// ---------------------------------------------------------------------------
__global__ void k_reorder4(
    const void* w11,const void* w12,const void* w21,const void* w22,
    const int* __restrict__ flagp,
    u16* o11,u16* o12,u16* o21,u16* o22)
{
  int blk = blockIdx.x;
  const void* win; u16* wout; int cin;
  if      (blk < 2304){ win=w11; wout=o11; cin=512; }
  else if (blk < 4608){ win=w12; wout=o12; cin=512; blk-=2304; }
  else if (blk < 5184){ win=w21; wout=o21; cin=128; blk-=4608; }
  else                { win=w22; wout=o22; cin=128; blk-=5184; }
  const int idx = blk * 256 + threadIdx.x;
  const int flg = *flagp;
  const int n9 = cin * 9;
  const int co = idx / n9;
  const int rem = idx - co * n9;
  const int ci = rem / 9;
  const int rs = rem - ci * 9;
  const u16 v = flg ? ((const u16*)win)[idx] : f2b(((const float*)win)[idx]);
  wout[co * n9 + rs * cin + ci] = v;
}

// ---------------------------------------------------------------------------
// Zero halos of the 3 padded tensors in one launch.
// ---------------------------------------------------------------------------
__global__ void k_halo3(u16* __restrict__ xT, u16* __restrict__ f1, u16* __restrict__ cf)
{
  int blk = blockIdx.x;
  u16* buf; int cmask, csh;
  if      (blk < 260){ buf = xT; cmask = 511; csh = 9; }
  else if (blk < 325){ buf = f1; cmask = 127; csh = 7; blk -= 260; }
  else               { buf = cf; cmask = 127; csh = 7; blk -= 325; }
  const int tid = blk * 256 + threadIdx.x;
  const int e  = tid * 8;
  const int cc = e & cmask;
  const int rem = e >> csh;
  const int hp = rem % 260;
  const int b  = rem / 260;
  int pix;
  if      (hp < 66)  pix = hp;
  else if (hp < 132) pix = 65 * 66 + (hp - 66);
  else if (hp < 196) pix = (hp - 132 + 1) * 66;
  else               pix = (hp - 196 + 1) * 66 + 65;
  uint4 z; z.x = 0; z.y = 0; z.z = 0; z.w = 0;
  *(uint4*)(buf + ((size_t)b * PPIX + pix) * (cmask + 1) + cc) = z;
}

// ---------------------------------------------------------------------------
// x transpose: [b][512][4096] (fp32 or bf16) -> padded bf16 [b][4356][512]
// ---------------------------------------------------------------------------
__global__ __launch_bounds__(256) void k_xT(
    const void* __restrict__ src, const int* __restrict__ flagp, u16* __restrict__ dst)
{
  const int t = threadIdx.x, wave = t >> 6, lane = t & 63;
  const int pb = blockIdx.x & 31, ct = (blockIdx.x >> 5) & 7, b = blockIdx.x >> 8;
  const int c  = ct * 64 + lane;
  const int p0 = pb * 128 + wave * 32;
  const size_t sbase = ((size_t)(b * 512) + c) * 4096 + p0;

  u16 vals[32];
  if (*flagp){
    const u16* s = (const u16*)src + sbase;
    #pragma unroll
    for (int k = 0; k < 4; ++k){
      uint4 v = *(const uint4*)(s + k * 8);
      __builtin_memcpy(&vals[k * 8], &v, 16);
    }
  } else {
    const float* s = (const float*)src + sbase;
    #pragma unroll
    for (int k = 0; k < 8; ++k){
      float4 v = *(const float4*)(s + k * 4);
      vals[k*4+0] = f2b(v.x); vals[k*4+1] = f2b(v.y);
      vals[k*4+2] = f2b(v.z); vals[k*4+3] = f2b(v.w);
    }
  }
  const int hrow = (p0 >> 6) * 66 + (p0 & 63) + 67;
  u16* d = dst + ((size_t)b * PPIX + hrow) * 512 + c;
  #pragma unroll
  for (int k = 0; k < 32; ++k) d[(size_t)k * 512] = vals[k];
}

// ---------------------------------------------------------------------------
// Fused sibling 3x3 convs, LDS-tiled implicit GEMM.
// v2: 128co x 64px tiles -> grid 512 = 2 blocks/CU (inter-block overlap
// hides the per-barrier vmcnt drain; R7 had 1 block/CU -> MfmaUtil 18%).
// Wave w: co [ (w>>1)*64, +64 ), px [ (w&1)*32, +32 ): 4x2 frags.
// ---------------------------------------------------------------------------
template<int CIN_, bool PADOUT_, bool DUALB_>
__global__ __launch_bounds__(256) void k_cgemm(
    const u16* __restrict__ xA, const u16* __restrict__ xB,
    const u16* __restrict__ wA, const u16* __restrict__ wB,
    const float* __restrict__ scale, const float* __restrict__ shift,
    u16* __restrict__ outA, u16* __restrict__ outBp, u16* __restrict__ outB2)
{
  constexpr int K9   = 9 * CIN_;
  constexpr int NCH  = CIN_ / 64;
  constexpr int OPIX = PADOUT_ ? PPIX : 4096;

  __shared__ __align__(16) u16 At[128 * 64];   // 16 KB
  __shared__ __align__(16) u16 Bt[64 * 64];    // 8 KB

  const int t = threadIdx.x;
  const int w = t >> 6, lane = t & 63;
  const int l16 = lane & 15, quad = lane >> 4;

  const int cid = blockIdx.x >> 8;           // conv id
  const int rem = blockIdx.x & 255;
  const int b   = rem >> 6;
  const int p0  = (rem & 63) << 6;           // 64-px tile

  const u16* xin = cid ? xB : xA;
  const u16* wK  = cid ? wB : wA;
  const float* sc = scale + cid * 128;
  const float* sh = shift + cid * 128;

  const int rowS = t >> 3;                         // 0..31
  const int sw   = ((t & 7) ^ (rowS & 7)) << 3;    // swizzled global column

  const u16* gA[4]; u16* lA[4];
  #pragma unroll
  for (int k = 0; k < 4; ++k){
    gA[k] = wK + (size_t)(k * 32 + rowS) * K9 + sw;
    lA[k] = At + k * 2048 + w * 512;
  }
  const u16* gB[2]; u16* lB[2];
  #pragma unroll
  for (int k = 0; k < 2; ++k){
    const int px = p0 + k * 32 + rowS;
    const int h = px >> 6, wc = px & 63;
    gB[k] = xin + ((size_t)b * PPIX + h * 66 + wc) * CIN_ + sw;
    lB[k] = Bt + k * 2048 + w * 512;
  }

  f32x4 acc[4][2];
  #pragma unroll
  for (int mi = 0; mi < 4; ++mi)
    #pragma unroll
    for (int ni = 0; ni < 2; ++ni){
      acc[mi][ni][0]=0.f; acc[mi][ni][1]=0.f; acc[mi][ni][2]=0.f; acc[mi][ni][3]=0.f;
    }

  const int wc4 = (w >> 1) << 6;   // wave co base
  const int wp4 = (w & 1) << 5;    // wave px base

  #pragma unroll 1
  for (int tap = 0; tap < 9; ++tap){
    const int tb = (tap / 3) * 66 + (tap % 3);
    #pragma unroll 1
    for (int cc = 0; cc < NCH; ++cc){
      const int offA = tap * CIN_ + cc * 64;
      const int offB = tb  * CIN_ + cc * 64;
      #pragma unroll
      for (int k = 0; k < 4; ++k) gload_lds16(gA[k] + offA, lA[k]);
      #pragma unroll
      for (int k = 0; k < 2; ++k) gload_lds16(gB[k] + offB, lB[k]);
      __syncthreads();
      #pragma unroll
      for (int ks = 0; ks < 2; ++ks){
        bf16x8 af[4], bf[2];
        const int col = ((ks * 4 + quad) ^ (l16 & 7)) << 3;
        #pragma unroll
        for (int mi = 0; mi < 4; ++mi)
          af[mi] = *(const bf16x8*)(At + ((wc4 + mi * 16 + l16) << 6) + col);
        #pragma unroll
        for (int ni = 0; ni < 2; ++ni)
          bf[ni] = *(const bf16x8*)(Bt + ((wp4 + ni * 16 + l16) << 6) + col);
        #pragma unroll
        for (int mi = 0; mi < 4; ++mi)
          #pragma unroll
          for (int ni = 0; ni < 2; ++ni)
            acc[mi][ni] = __builtin_amdgcn_mfma_f32_16x16x32_bf16(af[mi], bf[ni], acc[mi][ni], 0, 0, 0);
      }
      __syncthreads();
    }
  }

  u16* outp = cid ? outBp : outA;
  #pragma unroll
  for (int mi = 0; mi < 4; ++mi){
    #pragma unroll
    for (int ni = 0; ni < 2; ++ni){
      const int px = p0 + wp4 + ni * 16 + l16;
      const int opix = PADOUT_ ? ((px >> 6) * 66 + (px & 63) + 67) : px;
      const int co4 = wc4 + mi * 16 + quad * 4;
      u16 pk[4];
      #pragma unroll
      for (int rr = 0; rr < 4; ++rr)
        pk[rr] = f2b(fmaxf(acc[mi][ni][rr] * sc[co4 + rr] + sh[co4 + rr], 0.f));
      u64 pkv; __builtin_memcpy(&pkv, pk, 8);
      *(u64*)(outp + ((size_t)b * OPIX + opix) * 128 + co4) = pkv;
      if constexpr (DUALB_){
        if (cid){
          #pragma unroll
          for (int rr = 0; rr < 4; ++rr)
            outB2[((size_t)(b * 128) + co4 + rr) * 4096 + px] = pk[rr];
        }
      }
    }
  }
}

// ---------------------------------------------------------------------------
// 1x1 conv (MFMA), one wave per 16(co) x 16(px) tile; pixel-major input.
// EPI: 2 = +bias -> channel-major bf16
//      3 = +bias -> flag ? bf16 : fp32, channel-major (d_out heads)
//      4 = +bias -> qT hi/lo bf16 pair [b][4096][16]
//      5 = +bias -> V in PV-fragment-tiled layout (coalesced flash staging):
//          [b][js(4)][chunk(16)][cs(8)][ks(2)][quad(4)][l16(16)][8]
//      6 = CAM: gamma*acc + residual(xin2, padded pixel-major) -> padded pm out
// WPB_: weights indexed per batch (wK + b*CO*K) — used for CAM attn GEMM.
// ---------------------------------------------------------------------------
template<int CIN_, int CO_, int EPI_, bool SUM2_, bool PADIN_, bool PADOUT_, bool WPB_>
__global__ __launch_bounds__(256) void k_convT(
    const u16* __restrict__ xin, const u16* __restrict__ xin2,
    const u16* __restrict__ wK,
    const void* __restrict__ bias, const int* __restrict__ flagp,
    u16* __restrict__ outB, float* __restrict__ outF)
{
  constexpr int K    = CIN_;
  constexpr int MT   = CO_ / 16;
  constexpr int IPIX = PADIN_ ? PPIX : 4096;
  constexpr int OPIX = PADOUT_ ? PPIX : 4096;

  const int tid  = threadIdx.x;
  const int wave = tid >> 6;
  const int lane = tid & 63;
  const int l16  = lane & 15;
  const int quad = lane >> 4;

  int tile = blockIdx.x * 4 + wave;
  const int nt = tile & 255; tile >>= 8;
  const int mt = tile % MT;
  const int b  = tile / MT;

  const int p = nt * 16 + l16;
  const int h = p >> 6, wc = p & 63;

  const u16* wrow = wK + (WPB_ ? (size_t)b * CO_ * K : 0)
                       + (size_t)(mt * 16 + l16) * K + quad * 8;
  const u16* xb   = xin + (size_t)b * IPIX * CIN_ + quad * 8;

  f32x4 acc = {0.f, 0.f, 0.f, 0.f};

  const int poff = PADIN_ ? (h * 66 + wc + 67) : p;
  const u16* xrs = xb + (size_t)poff * CIN_;
  const u16* xrs2 = nullptr;
  if constexpr (SUM2_) xrs2 = xin2 + (size_t)b * IPIX * CIN_ + quad * 8 + (size_t)poff * CIN_;
  #pragma unroll
  for (int ci0 = 0; ci0 < CIN_; ci0 += 32){
    bf16x8 af = *(const bf16x8*)(wrow + ci0);
    bf16x8 bf;
    if constexpr (SUM2_){
      bf16x8 b1 = *(const bf16x8*)(xrs + ci0);
      bf16x8 b2 = *(const bf16x8*)(xrs2 + ci0);
      #pragma unroll
      for (int j = 0; j < 8; ++j)
        bf[j] = (short)f2b(b2f((u16)b1[j]) + b2f((u16)b2[j]));
    } else {
      bf = *(const bf16x8*)(xrs + ci0);
    }
    acc = __builtin_amdgcn_mfma_f32_16x16x32_bf16(af, bf, acc, 0, 0, 0);
  }

  const int flg = *flagp;

  if constexpr (EPI_ == 4){
    #pragma unroll
    for (int rr = 0; rr < 4; ++rr){
      const int co = quad * 4 + rr;   // MT == 1
      const float vv = acc[rr] + ldf(bias, co, flg);
      const u16 hb = f2b(vv);
      const float lo = vv - b2f(hb);
      const size_t qaddr = ((size_t)b * 4096 + p) * 16 + co;
      outB[qaddr] = hb;
      ((u16*)outF)[qaddr] = f2b(lo);
    }
  } else if constexpr (EPI_ == 5){
    // V tiled for coalesced staging in k_pam_flash. Element (c=co, j=p):
    // off = ((b*4+js)*16+chunk)*8192 + ((cs*2+ks)*64 + qd*16 + lc)*8 + jj
    const int js = p >> 10, chv = (p >> 6) & 15, ksv = (p >> 5) & 1;
    const int qd = (p >> 3) & 3, jj = p & 7;
    #pragma unroll
    for (int rr = 0; rr < 4; ++rr){
      const int lc = quad * 4 + rr;          // c & 15 ; cs == mt
      const float vv = acc[rr] + ldf(bias, mt * 16 + lc, flg);
      const size_t addr = ((size_t)((b * 4 + js) * 16 + chv)) * 8192
                        + (size_t)((((mt * 2 + ksv) * 64) + qd * 16 + lc) * 8 + jj);
      outB[addr] = f2b(vv);
    }
  } else if constexpr (EPI_ == 6){
    const float g = ldf(bias, 0, flg);
    const int opix = PADOUT_ ? (h * 66 + wc + 67) : p;
    const int co4 = mt * 16 + quad * 4;
    const size_t addr = ((size_t)b * OPIX + opix) * CO_ + co4;
    u64 rv = *(const u64*)(xin2 + (size_t)b * OPIX * CO_ + (size_t)opix * CO_ + co4);
    u16 rk[4]; __builtin_memcpy(rk, &rv, 8);
    u16 pk[4];
    #pragma unroll
    for (int rr = 0; rr < 4; ++rr)
      pk[rr] = f2b(g * acc[rr] + b2f(rk[rr]));
    u64 pkv; __builtin_memcpy(&pkv, pk, 8);
    *(u64*)(outB + addr) = pkv;
  } else {
    #pragma unroll
    for (int rr = 0; rr < 4; ++rr){
      const int co = mt * 16 + quad * 4 + rr;
      const float vv = acc[rr] + ldf(bias, co, flg);
      const size_t addr = ((size_t)(b * CO_) + co) * 4096 + p;
      if constexpr (EPI_ == 2) outB[addr] = f2b(vv);
      else { if (flg) outB[addr] = f2b(vv); else outF[addr] = vv; }
    }
  }
}

// ---------------------------------------------------------------------------
// PAM flash attention v8: TWO-PASS, dbuf V, one barrier/chunk (v5 structure)
// + TILED V GLOBAL LAYOUT for coalesced staging.
// History: v3 78us (2 barriers); v4 151us (no staging, latency exposed);
// v5 75.8us; v6 defer-max 91.7us (VGPR/occ, REVERTED); v7 +K-lds 77.8us
// (neutral, occ halved, REVERTED). Invariant across v3/v5/v7: Mfma ~16%,
// dur ~76-78 -> rate-limited by something occupancy/barrier-independent.
// Diagnosis: old vsrcB had 64 distinct cache lines per gload_lds wave-instr
// (c-major stride 8KB) -> TA address-serialization ~1Kcyc/chunk/block.
// v8: value conv writes V pre-tiled as the exact LDS image; staging reads
// are fully linear (t+256k)*16B -> 16 lines/instr, 4x fewer transactions.
// vdstO and all PV reads unchanged (LDS image byte-identical).
// Grid 1024 = b x 64 i-tile x 4 j-seg. Block 256 = 4 waves. LDS 40KB.
// ---------------------------------------------------------------------------
__global__ __launch_bounds__(256) void k_pam_flash(
    const u16* __restrict__ qTh, const u16* __restrict__ qTl,
    const u16* __restrict__ vt,
    u16* __restrict__ po, float* __restrict__ pm, float* __restrict__ pl)
{
  __shared__ __align__(16) u16 vls[2][1024 * 8]; // 2 x 16 KB double buffer
  __shared__ __align__(16) u16 pls[4][128 * 8];  // 8 KB, per-wave

  const int t    = threadIdx.x;
  const int wave = t >> 6, lane = t & 63;
  const int l16  = lane & 15, quad = lane >> 4;

  const int bid = blockIdx.x;
  const int js  = bid & 3, it = (bid >> 2) & 63, b = bid >> 8;
  const int i0  = it * 64;
  const int jbase = js * 1024;

  const u16* qTbh = qTh + ((size_t)b * 4096) * 16;
  const u16* qTbl = qTl + ((size_t)b * 4096) * 16;

  bf16x8 af_hl, af_h0 = {};
  {
    const int i = i0 + wave * 16 + l16;
    const u16* src = ((quad < 2) ? qTbh : qTbl) + (size_t)i * 16 + (quad & 1) * 8;
    *(uint4*)&af_hl = *(const uint4*)src;
    if (quad < 2) af_h0 = af_hl;
  }

  // Tiled V staging: fully linear global source, LDS image unchanged.
  const u16* vsrc = vt + ((size_t)(b * 4 + js) * 16) * 8192 + (size_t)t * 8;
  int vdstO[4];
  #pragma unroll
  for (int k = 0; k < 4; ++k) vdstO[k] = (wave * 64 + 256 * k) * 8;

  // Prologue: stage V chunk 0 into buffer 0; lands during pass A.
  #pragma unroll
  for (int k = 0; k < 4; ++k)
    gload_lds16(vsrc + (size_t)k * 2048, &vls[0][0] + vdstO[k]);

  // Pass A: segment row max (hi-only QK)
  float mloc[4] = {-3e38f, -3e38f, -3e38f, -3e38f};
  #pragma unroll 1
  for (int ch = 0; ch < 16; ++ch){
    #pragma unroll
    for (int ns = 0; ns < 4; ++ns){
      const int j = jbase + ch * 64 + ns * 16 + l16;
      bf16x8 bh;
      *(uint4*)&bh = *(const uint4*)(qTbh + (size_t)j * 16 + (quad & 1) * 8);
      f32x4 z = {0.f, 0.f, 0.f, 0.f};
      z = __builtin_amdgcn_mfma_f32_16x16x32_bf16(af_hl, bh, z, 0, 0, 0);
      #pragma unroll
      for (int r = 0; r < 4; ++r) mloc[r] = fmaxf(mloc[r], z[r]);
    }
  }
  float mrow[4];
  #pragma unroll
  for (int r = 0; r < 4; ++r){
    float mm = mloc[r];
    mm = fmaxf(mm, __shfl_xor(mm, 1));
    mm = fmaxf(mm, __shfl_xor(mm, 2));
    mm = fmaxf(mm, __shfl_xor(mm, 4));
    mm = fmaxf(mm, __shfl_xor(mm, 8));
    mrow[r] = mm;
  }

  const short oneb = (short)0x3F80;
  const bf16x8 vones = {oneb,oneb,oneb,oneb,oneb,oneb,oneb,oneb};

  f32x4 oacc[8];
  #pragma unroll
  for (int cs = 0; cs < 8; ++cs){ oacc[cs][0]=0.f; oacc[cs][1]=0.f; oacc[cs][2]=0.f; oacc[cs][3]=0.f; }
  f32x4 lacc = {0.f, 0.f, 0.f, 0.f};

  // Pass B: one barrier per chunk. Barrier at top drains vmcnt -> V(ch)
  // (issued last iteration) is in LDS, and all waves are done reading the
  // buffer we are about to overwrite with V(ch+1).
  #pragma unroll 1
  for (int ch = 0; ch < 16; ++ch){
    const int j0 = ch * 64;
    const int cur = ch & 1;
    __syncthreads();

    if (ch < 15){
      u16* nbuf = &vls[cur ^ 1][0];
      const u16* nsrc = vsrc + (size_t)(ch + 1) * 8192;
      #pragma unroll
      for (int k = 0; k < 4; ++k)
        gload_lds16(nsrc + (size_t)k * 2048, nbuf + vdstO[k]);
    }

    #pragma unroll
    for (int ns = 0; ns < 4; ++ns){
      const int j = jbase + j0 + ns * 16 + l16;
      bf16x8 bh, bl;
      *(uint4*)&bh = *(const uint4*)(qTbh + (size_t)j * 16 + (quad & 1) * 8);
      *(uint4*)&bl = *(const uint4*)(qTbl + (size_t)j * 16 + (quad & 1) * 8);
      f32x4 z = {0.f, 0.f, 0.f, 0.f};
      z = __builtin_amdgcn_mfma_f32_16x16x32_bf16(af_hl, bh, z, 0, 0, 0);
      z = __builtin_amdgcn_mfma_f32_16x16x32_bf16(af_h0, bl, z, 0, 0, 0);
      const int ks = ns >> 1;
      const int qp = (ns * 2 + (l16 >> 3)) & 3;
      #pragma unroll
      for (int r = 0; r < 4; ++r){
        const float p = __expf(z[r] - mrow[r]);
        pls[wave][(ks * 64 + qp * 16 + quad * 4 + r) * 8 + (l16 & 7)] = f2b_trunc(p);
      }
    }

    const u16* vcur = &vls[cur][0];
    #pragma unroll
    for (int ks = 0; ks < 2; ++ks){
      bf16x8 pf = *(const bf16x8*)(pls[wave] + ((ks * 64 + lane) << 3));
      #pragma unroll
      for (int cs = 0; cs < 8; ++cs){
        bf16x8 vf = *(const bf16x8*)(vcur + (((cs * 2 + ks) * 64 + lane) << 3));
        oacc[cs] = __builtin_amdgcn_mfma_f32_16x16x32_bf16(pf, vf, oacc[cs], 0, 0, 0);
      }
      lacc = __builtin_amdgcn_mfma_f32_16x16x32_bf16(pf, vones, lacc, 0, 0, 0);
    }
  }

  u16* pob = po + (size_t)bid * 64 * 128;
  #pragma unroll
  for (int cs = 0; cs < 8; ++cs)
    #pragma unroll
    for (int r = 0; r < 4; ++r)
      pob[(wave * 16 + quad * 4 + r) * 128 + cs * 16 + l16] = f2b(oacc[cs][r]);
  if (l16 == 0){
    #pragma unroll
    for (int r = 0; r < 4; ++r){
      pm[(size_t)bid * 64 + wave * 16 + quad * 4 + r] = mrow[r];
      pl[(size_t)bid * 64 + wave * 16 + quad * 4 + r] = lacc[r];
    }
  }
}

// ---------------------------------------------------------------------------
// PAM combine (pixel-major): merge 4 j-seg partials, gamma + residual.
// ---------------------------------------------------------------------------
__global__ __launch_bounds__(256) void k_pam_comb2(
    const u16* __restrict__ po, const float* __restrict__ pm, const float* __restrict__ pl,
    const void* __restrict__ gptr, const int* __restrict__ flagp,
    u16* __restrict__ featT)
{
  __shared__ float wgt[4][64];
  const int t  = threadIdx.x;
  const int it = blockIdx.x & 63, b = blockIdx.x >> 6;
  const int base = (b * 64 + it) * 4;
  if (t < 64){
    const float m0 = pm[(size_t)(base+0)*64 + t];
    const float m1 = pm[(size_t)(base+1)*64 + t];
    const float m2 = pm[(size_t)(base+2)*64 + t];
    const float m3 = pm[(size_t)(base+3)*64 + t];
    const float M  = fmaxf(fmaxf(m0, m1), fmaxf(m2, m3));
    const float e0 = __expf(m0 - M), e1 = __expf(m1 - M);
    const float e2 = __expf(m2 - M), e3 = __expf(m3 - M);
    const float L  = pl[(size_t)(base+0)*64+t]*e0 + pl[(size_t)(base+1)*64+t]*e1
                   + pl[(size_t)(base+2)*64+t]*e2 + pl[(size_t)(base+3)*64+t]*e3;
    const float li = 1.0f / L;
    wgt[0][t] = e0*li; wgt[1][t] = e1*li; wgt[2][t] = e2*li; wgt[3][t] = e3*li;
  }
  __syncthreads();
  const float g = ldf(gptr, 0, *flagp);
  const int c = t & 127, ih = t >> 7;
  const int i0 = it * 64;
  for (int st = 0; st < 32; ++st){
    const int il = ih + st * 2;
    float acc = 0.f;
    #pragma unroll
    for (int s = 0; s < 4; ++s)
      acc += wgt[s][il] * b2f(po[((size_t)(base+s)*64 + il)*128 + c]);
    const int i = i0 + il;
    const int pix = (i >> 6) * 66 + (i & 63) + 67;
    u16* addr = featT + ((size_t)b * PPIX + pix) * 128 + c;
    *addr = f2b(g * acc + b2f(*addr));
  }
}

// ---------------------------------------------------------------------------
// CAM energy + softmax via MFMA. Grid 32 = b(4) x ct(8); block 256.
// ---------------------------------------------------------------------------
__global__ __launch_bounds__(256) void k_cam_energy(
    const u16* __restrict__ f, u16* __restrict__ attnc)
{
  __shared__ float els[16][132];
  const int t = threadIdx.x, wave = t >> 6, lane = t & 63;
  const int l16 = lane & 15, quad = lane >> 4;
  const int ct = blockIdx.x & 7, b = blockIdx.x >> 3;
  const u16* fb = f + (size_t)b * 128 * 4096;
  const int c0 = ct * 16;
  const int d0 = wave * 32;

  f32x4 e0 = {0.f,0.f,0.f,0.f}, e1 = {0.f,0.f,0.f,0.f};
  #pragma unroll 2
  for (int k0 = 0; k0 < 4096; k0 += 32){
    bf16x8 afr, bf0, bf1;
    *(uint4*)&afr = *(const uint4*)(fb + (size_t)(c0 + l16) * 4096 + k0 + quad * 8);
    *(uint4*)&bf0 = *(const uint4*)(fb + (size_t)(d0 + l16) * 4096 + k0 + quad * 8);
    *(uint4*)&bf1 = *(const uint4*)(fb + (size_t)(d0 + 16 + l16) * 4096 + k0 + quad * 8);
    e0 = __builtin_amdgcn_mfma_f32_16x16x32_bf16(afr, bf0, e0, 0, 0, 0);
    e1 = __builtin_amdgcn_mfma_f32_16x16x32_bf16(afr, bf1, e1, 0, 0, 0);
  }
  #pragma unroll
  for (int r = 0; r < 4; ++r){
    els[quad * 4 + r][d0 + l16]      = e0[r];
    els[quad * 4 + r][d0 + 16 + l16] = e1[r];
  }
  __syncthreads();
  const int c = wave * 4 + quad, sg = l16;
  float mn = 3e38f;
  float ev[8];
  #pragma unroll
  for (int k = 0; k < 8; ++k){ ev[k] = els[c][sg * 8 + k]; mn = fminf(mn, ev[k]); }
  mn = fminf(mn, __shfl_xor(mn, 1));
  mn = fminf(mn, __shfl_xor(mn, 2));
  mn = fminf(mn, __shfl_xor(mn, 4));
  mn = fminf(mn, __shfl_xor(mn, 8));
  float s = 0.f;
  #pragma unroll
  for (int k = 0; k < 8; ++k){ ev[k] = __expf(mn - ev[k]); s += ev[k]; }
  s += __shfl_xor(s, 1); s += __shfl_xor(s, 2);
  s += __shfl_xor(s, 4); s += __shfl_xor(s, 8);
  const float inv = 1.0f / s;
  u16* dst = attnc + ((size_t)b * 128 + c0 + c) * 128 + sg * 8;
  #pragma unroll
  for (int k = 0; k < 8; ++k) dst[k] = f2b(ev[k] * inv);
}

// ---------------------------------------------------------------------------
extern "C" void kernel_launch(void* const* d_in, const int* in_sizes, int n_in,
                              void* d_out, int out_size, void* d_ws, size_t ws_size,
                              hipStream_t stream)
{
  (void)in_sizes; (void)n_in; (void)out_size; (void)ws_size;

  const void* x    = d_in[0];
  const void* w11  = d_in[1];
  const void* g11  = d_in[2];
  const void* b11  = d_in[3];
  const void* m11  = d_in[4];
  const void* v11  = d_in[5];
  const void* w12  = d_in[6];
  const void* g12  = d_in[7];
  const void* b12  = d_in[8];
  const void* m12  = d_in[9];
  const void* v12  = d_in[10];
  const void* kw   = d_in[11];
  const void* kb   = d_in[12];
  const void* vw   = d_in[13];
  const void* vb   = d_in[14];
  const void* pgam = d_in[15];
  const void* cgam = d_in[16];
  const void* w21  = d_in[17];
  const void* g21  = d_in[18];
  const void* b21  = d_in[19];
  const void* m21  = d_in[20];
  const void* v21  = d_in[21];
  const void* w22  = d_in[22];
  const void* g22  = d_in[23];
  const void* b22  = d_in[24];
  const void* m22  = d_in[25];
  const void* v22  = d_in[26];
  const void* w31  = d_in[27];
  const void* b31  = d_in[28];
  const void* w32  = d_in[29];
  const void* b32  = d_in[30];
  const void* w4   = d_in[31];
  const void* b4   = d_in[32];

  char* wsb = (char*)d_ws;
  size_t off = 0;
  auto alloc = [&](size_t bytes) -> void* {
    void* pp = wsb + off;
    off += (bytes + 255) & ~(size_t)255;
    return pp;
  };
  u16*   xT      = (u16*)alloc((size_t)4 * PPIX * 512 * 2);  // dead after trunk -> po
  u16*   feat1T  = (u16*)alloc((size_t)4 * PPIX * 128 * 2);  // padded; later pa_feat (in-place)
  u16*   feat2T  = (u16*)alloc((size_t)4 * PPIX * 128 * 2);  // padded (residual reads)
  u16*   feat2cm = (u16*)alloc((size_t)4 * 128 * HW * 2);    // channel-major (CAM energy)
  u16*   cafeatT = (u16*)alloc((size_t)4 * PPIX * 128 * 2);  // padded
  u16*   vbuf    = (u16*)alloc((size_t)4 * 128 * HW * 2);    // V tiled (PAM); later pa_conv_T (unpadded)
  u16*   caconvT = (u16*)alloc((size_t)4 * HW * 128 * 2);    // unpadded pixel-major
  u16*   qTh     = (u16*)alloc((size_t)4 * HW * 16 * 2);
  u16*   qTl     = (u16*)alloc((size_t)4 * HW * 16 * 2);
  float* pm      = (float*)alloc((size_t)1024 * 64 * 4);
  float* pl      = (float*)alloc((size_t)1024 * 64 * 4);
  u16*   attnc   = (u16*)alloc((size_t)4 * 128 * 128 * 2);
  float* scale   = (float*)alloc(512 * 4);
  float* shift   = (float*)alloc(512 * 4);
  u16*   w11r    = (u16*)alloc((size_t)128 * 4608 * 2);
  u16*   w12r    = (u16*)alloc((size_t)128 * 4608 * 2);
  u16*   w21r    = (u16*)alloc((size_t)128 * 1152 * 2);
  u16*   w22r    = (u16*)alloc((size_t)128 * 1152 * 2);
  u16*   kwb     = (u16*)alloc((size_t)16 * 128 * 2);
  u16*   vwb     = (u16*)alloc((size_t)128 * 128 * 2);
  u16*   w31b    = (u16*)alloc((size_t)64 * 128 * 2);
  u16*   w32b    = (u16*)alloc((size_t)64 * 128 * 2);
  u16*   w4b     = (u16*)alloc((size_t)64 * 128 * 2);
  int*   flag    = (int*)alloc(256);
  u16*   po      = xT;   // 16.8 MB <= xT's 17.8 MB; xT dead after trunk convs

  // prep
  k_prep<<<1, 512, 0, stream>>>((const u32*)x,
                                g11,b11,m11,v11, g12,b12,m12,v12,
                                g21,b21,m21,v21, g22,b22,m22,v22, flag, scale, shift);
  k_halo3<<<390, 256, 0, stream>>>(xT, feat1T, cafeatT);
  k_xT<<<1024, 256, 0, stream>>>(x, flag, xT);
  k_reorder4<<<5760, 256, 0, stream>>>(w11, w12, w21, w22, flag, w11r, w12r, w21r, w22r);
  k_cvt5<<<42, 256, 0, stream>>>(kw, vw, w31, w32, w4, flag, kwb, vwb, w31b, w32b, w4b);

  // trunk convs, fused LDS-GEMM, 2 blocks/CU
  k_cgemm<512, true, true><<<512, 256, 0, stream>>>(
      xT, xT, w11r, w12r, scale, shift, feat1T, feat2T, feat2cm);

  // PAM
  k_convT<128,16,4,false,true,false,false><<<256,256,0,stream>>>(
      feat1T, nullptr, kwb, kb, flag, qTh, (float*)qTl);
  k_convT<128,128,5,false,true,false,false><<<2048,256,0,stream>>>(
      feat1T, nullptr, vwb, vb, flag, vbuf, nullptr);          // -> V tiled
  k_pam_flash<<<1024, 256, 0, stream>>>(qTh, qTl, vbuf, po, pm, pl);
  k_pam_comb2<<<256, 256, 0, stream>>>(po, pm, pl, pgam, flag, feat1T);  // -> pa_feat

  // CAM: MFMA energy+softmax, then MFMA GEMM attn @ f with residual epilogue
  k_cam_energy<<<32, 256, 0, stream>>>(feat2cm, attnc);
  k_convT<128,128,6,false,true,true,true><<<2048,256,0,stream>>>(
      feat2T, feat2T, attnc, cgam, flag, cafeatT, nullptr);

  // second convs, fused LDS-GEMM, 2 blocks/CU
  k_cgemm<128, false, false><<<512, 256, 0, stream>>>(
      feat1T, cafeatT, w21r, w22r, scale + 256, shift + 256, vbuf, caconvT, nullptr);

  // heads -> d_out [3][4][64][4096], channel-major, dtype per flag
  const size_t SEC = (size_t)4 * 64 * HW;
  u16*   outB = (u16*)d_out;
  float* outF = (float*)d_out;
  k_convT<128,64,3,false,false,false,false><<<1024,256,0,stream>>>(
      vbuf,    nullptr, w31b, b31, flag, outB,           outF);
  k_convT<128,64,3,false,false,false,false><<<1024,256,0,stream>>>(
      caconvT, nullptr, w32b, b32, flag, outB + SEC,     outF + SEC);
  k_convT<128,64,3,true ,false,false,false><<<1024,256,0,stream>>>(
      vbuf,    caconvT, w4b,  b4,  flag, outB + 2 * SEC, outF + 2 * SEC);
}